// Round 1
// baseline (8356.528 us; speedup 1.0000x reference)
//
#include <hip/hip_runtime.h>
#include <math.h>

#define HW 9216
#define WIDTH 96
#define CIN 512
#define OFFC 18
#define NK 9
#define FSTRIDE (CIN*HW)          // 4718592 floats
#define RSTRIDE (256*HW)          // 2359296 floats
#define OFFSTRIDE (OFFC*HW)       // 165888 floats
#define OFFPSTRIDE (8*OFFC*HW)    // 1327104 floats
#define TABSTRIDE (NK*HW)         // 82944 entries (int4/float4)

// ---------------- concat: f[b] = [sup_or_ref, ref] ----------------
__global__ void k_concat(const float* __restrict__ datas, float* __restrict__ f) {
  int b = blockIdx.z;
  int i = blockIdx.x * 256 + threadIdx.x;            // < CIN*HW
  const float* lo = datas + (size_t)(1 - b) * RSTRIDE; // b0(tt): ref ; b1(tk): sup
  const float* hi = datas + RSTRIDE;                   // ref
  float v = (i < RSTRIDE) ? lo[i] : hi[i - RSTRIDE];
  f[(size_t)b * FSTRIDE + i] = v;
}

// ---------------- offset conv 3x3, 512 -> 18 (partial over 64-c chunk) ----
__global__ void __launch_bounds__(256) k_offconv(const float* __restrict__ f,
                                                 const float* __restrict__ ow,
                                                 float* __restrict__ offp) {
  __shared__ __align__(16) float ws_[64][168];  // [cc][oc*9+k], row padded for b128
  const int tid = threadIdx.x;
  const int b = blockIdx.z;
  const int c0 = blockIdx.y * 64;

  for (int oc = 0; oc < OFFC; ++oc) {
    const float* src = ow + (size_t)oc * (CIN * 9) + (size_t)c0 * 9;
    for (int j = tid; j < 576; j += 256)
      ws_[j / 9][oc * 9 + (j % 9)] = src[j];
  }
  __syncthreads();

  const int px = blockIdx.x * 256 + tid;  // < 9216
  const int h = px / WIDTH, w = px - h * WIDTH;
  const float* fb = f + (size_t)b * FSTRIDE;
  float acc[18];
#pragma unroll
  for (int i = 0; i < 18; ++i) acc[i] = 0.f;

  for (int cc = 0; cc < 64; ++cc) {
    const float* xb = fb + (size_t)(c0 + cc) * HW;
    float v[9];
#pragma unroll
    for (int r = 0; r < 3; ++r) {
      int hh = h + r - 1;
      bool rv = (hh >= 0) && (hh < 96);
#pragma unroll
      for (int cl = 0; cl < 3; ++cl) {
        int wwp = w + cl - 1;
        bool cv = (wwp >= 0) && (wwp < 96);
        v[r * 3 + cl] = (rv && cv) ? xb[hh * WIDTH + wwp] : 0.f;
      }
    }
    const float4* wrow = (const float4*)(&ws_[cc][0]);
#pragma unroll
    for (int q = 0; q < 40; ++q) {
      float4 wv = wrow[q];
      acc[(q * 4 + 0) / 9] += v[(q * 4 + 0) % 9] * wv.x;
      acc[(q * 4 + 1) / 9] += v[(q * 4 + 1) % 9] * wv.y;
      acc[(q * 4 + 2) / 9] += v[(q * 4 + 2) % 9] * wv.z;
      acc[(q * 4 + 3) / 9] += v[(q * 4 + 3) % 9] * wv.w;
    }
    acc[17] += v[7] * ws_[cc][160] + v[8] * ws_[cc][161];
  }

  float* dst = offp + (size_t)b * OFFPSTRIDE + (size_t)blockIdx.y * (OFFC * HW) + px;
#pragma unroll
  for (int oc = 0; oc < 18; ++oc) dst[(size_t)oc * HW] = acc[oc];
}

// ---------------- reduce 8 partials + bias ----------------
__global__ void k_offreduce(const float* __restrict__ offp, const float* __restrict__ ob,
                            float* __restrict__ off) {
  int b = blockIdx.z;
  int i = blockIdx.x * 256 + threadIdx.x;  // < OFFC*HW
  int oc = i / HW;
  const float* p = offp + (size_t)b * OFFPSTRIDE + i;
  float s = ob[oc];
#pragma unroll
  for (int j = 0; j < 8; ++j) s += p[(size_t)j * (OFFC * HW)];
  off[(size_t)b * OFFSTRIDE + i] = s;
}

// ---------------- bilinear tables: per (k, px): 4 indices + 4 weights ------
__global__ void k_table(const float* __restrict__ off, int4* __restrict__ tabi,
                        float4* __restrict__ tabw) {
  int b = blockIdx.z, k = blockIdx.y;
  int px = blockIdx.x * 256 + threadIdx.x;
  const float* ob = off + (size_t)b * OFFSTRIDE;
  float dy = ob[(size_t)(2 * k) * HW + px];
  float dx = ob[(size_t)(2 * k + 1) * HW + px];
  int h = px / WIDTH, w = px - h * WIDTH;
  float py = (float)(h - 1 + k / 3) + dy;
  float pxx = (float)(w - 1 + k % 3) + dx;
  float y0 = floorf(py), x0 = floorf(pxx);
  float ay = py - y0, ax = pxx - x0;
  float wy[2] = {1.f - ay, ay}, wx[2] = {1.f - ax, ax};
  int idx[4]; float wt[4];
#pragma unroll
  for (int t = 0; t < 4; ++t) {
    float oy = y0 + (float)(t >> 1);
    float ox = x0 + (float)(t & 1);
    bool valid = (oy >= 0.f) && (oy <= 95.f) && (ox >= 0.f) && (ox <= 95.f);
    int yi = (int)fminf(fmaxf(oy, 0.f), 95.f);
    int xi = (int)fminf(fmaxf(ox, 0.f), 95.f);
    idx[t] = yi * WIDTH + xi;
    wt[t] = valid ? wy[t >> 1] * wx[t & 1] : 0.f;
  }
  size_t e = (size_t)b * TABSTRIDE + (size_t)k * HW + px;
  tabi[e] = make_int4(idx[0], idx[1], idx[2], idx[3]);
  tabw[e] = make_float4(wt[0], wt[1], wt[2], wt[3]);
}

// ---------------- sampled_k[c][px] ----------------
__global__ void k_sample(const float* __restrict__ xA, const float* __restrict__ xB,
                         const int4* __restrict__ tabi, const float4* __restrict__ tabw,
                         int k, float* __restrict__ samp) {
  int b = blockIdx.z, c = blockIdx.y;
  int px = blockIdx.x * 256 + threadIdx.x;
  const float* x = ((b == 0) ? xA : xB) + (size_t)c * HW;
  size_t e = (size_t)b * TABSTRIDE + (size_t)k * HW + px;
  int4 id = tabi[e];
  float4 wt = tabw[e];
  samp[(size_t)b * FSTRIDE + (size_t)c * HW + px] =
      wt.x * x[id.x] + wt.y * x[id.y] + wt.z * x[id.z] + wt.w * x[id.w];
}

// ---------------- fp32 GEMM: Y[M,HW] (+)= dw_k[M,C] * samp[C,HW] -----------
__global__ void __launch_bounds__(256) k_gemm(const float* __restrict__ dw,
                                              const float* __restrict__ samp,
                                              float* __restrict__ y,
                                              int k, int C, int beta0) {
  __shared__ __align__(16) float As[16][64];
  __shared__ __align__(16) float Bs[16][64];
  const int tid = threadIdx.x;
  const int b = blockIdx.z;
  const int n0 = blockIdx.x * 64, m0 = blockIdx.y * 64;
  const float* B = samp + (size_t)b * FSTRIDE;
  float* Y = y + (size_t)b * FSTRIDE;
  const int tx = tid & 15, ty = tid >> 4;
  float acc[4][4] = {};

  for (int kc = 0; kc < C; kc += 16) {
#pragma unroll
    for (int i = tid; i < 1024; i += 256) {
      int kk = i & 15, mm = i >> 4;
      As[kk][mm] = dw[((size_t)(m0 + mm) * C + (kc + kk)) * 9 + k];
    }
#pragma unroll
    for (int i = tid; i < 1024; i += 256) {
      int kk = i >> 6, nn = i & 63;
      Bs[kk][nn] = B[(size_t)(kc + kk) * HW + n0 + nn];
    }
    __syncthreads();
#pragma unroll
    for (int kk = 0; kk < 16; ++kk) {
      float4 av = *(const float4*)&As[kk][ty * 4];
      float4 bv = *(const float4*)&Bs[kk][tx * 4];
      float a_[4] = {av.x, av.y, av.z, av.w};
      float b_[4] = {bv.x, bv.y, bv.z, bv.w};
#pragma unroll
      for (int i = 0; i < 4; ++i)
#pragma unroll
        for (int j = 0; j < 4; ++j) acc[i][j] += a_[i] * b_[j];
    }
    __syncthreads();
  }

#pragma unroll
  for (int i = 0; i < 4; ++i) {
    float* row = Y + (size_t)(m0 + ty * 4 + i) * HW + n0 + tx * 4;
    float4 v = make_float4(acc[i][0], acc[i][1], acc[i][2], acc[i][3]);
    if (!beta0) {
      float4 o = *(const float4*)row;
      v.x += o.x; v.y += o.y; v.z += o.z; v.w += o.w;
    }
    *(float4*)row = v;
  }
}

// ---------------- GroupNorm stats ----------------
__global__ void k_gnstats(const float* __restrict__ y, float2* __restrict__ stat, int CperG) {
  int b = blockIdx.z, g = blockIdx.x;
  const float* p = y + (size_t)b * FSTRIDE + (size_t)g * CperG * HW;
  int n = CperG * HW;
  float s = 0.f, q = 0.f;
  for (int i = threadIdx.x; i < n; i += 256) { float v = p[i]; s += v; q += v * v; }
  __shared__ float ss[256], qs[256];
  ss[threadIdx.x] = s; qs[threadIdx.x] = q;
  __syncthreads();
  for (int d = 128; d > 0; d >>= 1) {
    if (threadIdx.x < d) { ss[threadIdx.x] += ss[threadIdx.x + d]; qs[threadIdx.x] += qs[threadIdx.x + d]; }
    __syncthreads();
  }
  if (threadIdx.x == 0) {
    float m = ss[0] / n;
    float var = qs[0] / n - m * m;
    stat[b * 32 + g] = make_float2(m, rsqrtf(var + 1e-5f));
  }
}

// ---------------- GroupNorm apply + ReLU ----------------
__global__ void k_gnapply(const float* __restrict__ y, const float2* __restrict__ stat,
                          const float* __restrict__ gamma, const float* __restrict__ beta,
                          float* __restrict__ out, int CperG, size_t ostride) {
  int b = blockIdx.z;
  int i = blockIdx.x * 256 + threadIdx.x;  // < C*HW
  int c = i / HW;
  float2 st = stat[b * 32 + c / CperG];
  float v = y[(size_t)b * FSTRIDE + i];
  v = (v - st.x) * st.y * gamma[c] + beta[c];
  out[(size_t)b * ostride + i] = fmaxf(v, 0.f);
}

// ---------------- cosine-sim softmax weight per pixel ----------------
__global__ void k_cos(const float* __restrict__ res, float* __restrict__ wpix) {
  int px = blockIdx.x * 256 + threadIdx.x;
  float saa = 0.f, sbb = 0.f, sab = 0.f;
  for (int c = 0; c < 256; ++c) {
    float a = res[(size_t)c * HW + px];
    float bb = res[RSTRIDE + (size_t)c * HW + px];
    saa += a * a; sbb += bb * bb; sab += a * bb;
  }
  float na = sqrtf(saa), nb = sqrtf(sbb);
  float ttw = saa / fmaxf(na * na, 1e-8f);
  float tkw = sab / fmaxf(na * nb, 1e-8f);
  float m = fmaxf(ttw, tkw);
  float e0 = expf(ttw - m), e1 = expf(tkw - m);
  wpix[px] = e0 / (e0 + e1);
}

// ---------------- final blend ----------------
__global__ void k_combine(const float* __restrict__ res, const float* __restrict__ wpix,
                          float* __restrict__ out) {
  int i = blockIdx.x * 256 + threadIdx.x;  // < RSTRIDE
  int px = i % HW;
  float w0 = wpix[px];
  out[i] = w0 * res[i] + (1.f - w0) * res[RSTRIDE + i];
}

extern "C" void kernel_launch(void* const* d_in, const int* in_sizes, int n_in,
                              void* d_out, int out_size, void* d_ws, size_t ws_size,
                              hipStream_t stream) {
  const float* datas = (const float*)d_in[0];
  const float* ow[4] = {(const float*)d_in[1], (const float*)d_in[6],
                        (const float*)d_in[11], (const float*)d_in[16]};
  const float* ob[4] = {(const float*)d_in[2], (const float*)d_in[7],
                        (const float*)d_in[12], (const float*)d_in[17]};
  const float* dw[4] = {(const float*)d_in[3], (const float*)d_in[8],
                        (const float*)d_in[13], (const float*)d_in[18]};
  const float* gg[4] = {(const float*)d_in[4], (const float*)d_in[9],
                        (const float*)d_in[14], (const float*)d_in[19]};
  const float* gb[4] = {(const float*)d_in[5], (const float*)d_in[10],
                        (const float*)d_in[15], (const float*)d_in[20]};

  float* ws = (float*)d_ws;
  float* f    = ws;                       // 2*FSTRIDE
  float* y    = f + 2 * (size_t)FSTRIDE;  // 2*FSTRIDE
  float* samp = y + 2 * (size_t)FSTRIDE;  // 2*FSTRIDE
  float* offp = samp + 2 * (size_t)FSTRIDE;       // 2*OFFPSTRIDE
  float* off  = offp + 2 * (size_t)OFFPSTRIDE;    // 2*OFFSTRIDE
  float4* tabw = (float4*)(off + 2 * (size_t)OFFSTRIDE);   // 2*TABSTRIDE float4
  int4*   tabi = (int4*)(tabw + 2 * (size_t)TABSTRIDE);    // 2*TABSTRIDE int4
  float* res  = (float*)(tabi + 2 * (size_t)TABSTRIDE);    // 2*RSTRIDE
  float* wpix = res + 2 * (size_t)RSTRIDE;                 // HW
  float2* stat = (float2*)(wpix + HW);                     // 2*32

  dim3 blk(256);
  k_concat<<<dim3(FSTRIDE / 256, 1, 2), blk, 0, stream>>>(datas, f);

  for (int l = 0; l < 4; ++l) {
    int Cx = (l < 3) ? 512 : 256;
    k_offconv<<<dim3(36, 8, 2), blk, 0, stream>>>(f, ow[l], offp);
    k_offreduce<<<dim3(OFFC * HW / 256, 1, 2), blk, 0, stream>>>(offp, ob[l], off);
    k_table<<<dim3(36, 9, 2), blk, 0, stream>>>(off, tabi, tabw);
    const float* xA = (l < 3) ? f : (datas + RSTRIDE);            // b0 (tt)
    const float* xB = (l < 3) ? (f + (size_t)FSTRIDE) : datas;    // b1 (tk)
    for (int k = 0; k < 9; ++k) {
      k_sample<<<dim3(36, Cx, 2), blk, 0, stream>>>(xA, xB, tabi, tabw, k, samp);
      k_gemm<<<dim3(144, Cx / 64, 2), blk, 0, stream>>>(dw[l], samp, y, k, Cx, k == 0);
    }
    k_gnstats<<<dim3(32, 1, 2), blk, 0, stream>>>(y, stat, Cx / 32);
    float* fo = (l < 3) ? f : res;
    size_t ostride = (l < 3) ? (size_t)FSTRIDE : (size_t)RSTRIDE;
    k_gnapply<<<dim3(Cx * HW / 256, 1, 2), blk, 0, stream>>>(y, stat, gg[l], gb[l], fo,
                                                             Cx / 32, ostride);
  }

  k_cos<<<dim3(HW / 256), blk, 0, stream>>>(res, wpix);
  k_combine<<<dim3(RSTRIDE / 256), blk, 0, stream>>>(res, wpix, (float*)d_out);
}

// Round 2
// 2789.513 us; speedup vs baseline: 2.9957x; 2.9957x over previous
//
#include <hip/hip_runtime.h>
#include <math.h>

#define HW 9216
#define WIDTH 96
#define OFFC 18
#define FSTRIDE (512*HW)          // 4718592
#define RSTRIDE (256*HW)          // 2359296
#define OFFSTRIDE (OFFC*HW)       // 165888
#define OFFPSTRIDE (8*OFFC*HW)    // 1327104
#define TABSTRIDE (9*HW)          // 82944

typedef __attribute__((ext_vector_type(8))) short bf16x8;
typedef __attribute__((ext_vector_type(4))) float f32x4;
typedef __attribute__((ext_vector_type(8))) unsigned short u16x8;

__device__ __forceinline__ unsigned short f2bf(float f) {
  unsigned int u = __float_as_uint(f);
  u += 0x7FFFu + ((u >> 16) & 1u);   // RNE
  return (unsigned short)(u >> 16);
}

#define GLDS(g, l) __builtin_amdgcn_global_load_lds( \
    (const __attribute__((address_space(1))) unsigned int*)(g), \
    (__attribute__((address_space(3))) unsigned int*)(l), 16, 0, 0)

// ---------------- concat: f[b] = [sup_or_ref, ref] ----------------
__global__ void k_concat(const float* __restrict__ datas, float* __restrict__ f) {
  int b = blockIdx.z;
  int i = blockIdx.x * 256 + threadIdx.x;
  const float* lo = datas + (size_t)(1 - b) * RSTRIDE;
  const float* hi = datas + RSTRIDE;
  float v = (i < RSTRIDE) ? lo[i] : hi[i - RSTRIDE];
  f[(size_t)b * FSTRIDE + i] = v;
}

// ---------------- offset conv 3x3, 512 -> 18 (partial over 64-c chunk) ----
__global__ void __launch_bounds__(256) k_offconv(const float* __restrict__ f,
                                                 const float* __restrict__ ow,
                                                 float* __restrict__ offp) {
  __shared__ __align__(16) float ws_[64][168];
  const int tid = threadIdx.x;
  const int b = blockIdx.z;
  const int c0 = blockIdx.y * 64;

  for (int oc = 0; oc < OFFC; ++oc) {
    const float* src = ow + (size_t)oc * (512 * 9) + (size_t)c0 * 9;
    for (int j = tid; j < 576; j += 256)
      ws_[j / 9][oc * 9 + (j % 9)] = src[j];
  }
  __syncthreads();

  const int px = blockIdx.x * 256 + tid;
  const int h = px / WIDTH, w = px - h * WIDTH;
  const float* fb = f + (size_t)b * FSTRIDE;
  float acc[18];
#pragma unroll
  for (int i = 0; i < 18; ++i) acc[i] = 0.f;

  for (int cc = 0; cc < 64; ++cc) {
    const float* xb = fb + (size_t)(c0 + cc) * HW;
    float v[9];
#pragma unroll
    for (int r = 0; r < 3; ++r) {
      int hh = h + r - 1;
      bool rv = (hh >= 0) && (hh < 96);
#pragma unroll
      for (int cl = 0; cl < 3; ++cl) {
        int wwp = w + cl - 1;
        bool cv = (wwp >= 0) && (wwp < 96);
        v[r * 3 + cl] = (rv && cv) ? xb[hh * WIDTH + wwp] : 0.f;
      }
    }
    const float4* wrow = (const float4*)(&ws_[cc][0]);
#pragma unroll
    for (int q = 0; q < 40; ++q) {
      float4 wv = wrow[q];
      acc[(q * 4 + 0) / 9] += v[(q * 4 + 0) % 9] * wv.x;
      acc[(q * 4 + 1) / 9] += v[(q * 4 + 1) % 9] * wv.y;
      acc[(q * 4 + 2) / 9] += v[(q * 4 + 2) % 9] * wv.z;
      acc[(q * 4 + 3) / 9] += v[(q * 4 + 3) % 9] * wv.w;
    }
    acc[17] += v[7] * ws_[cc][160] + v[8] * ws_[cc][161];
  }

  float* dst = offp + (size_t)b * OFFPSTRIDE + (size_t)blockIdx.y * (OFFC * HW) + px;
#pragma unroll
  for (int oc = 0; oc < 18; ++oc) dst[(size_t)oc * HW] = acc[oc];
}

// ---------------- reduce 8 partials + bias ----------------
__global__ void k_offreduce(const float* __restrict__ offp, const float* __restrict__ ob,
                            float* __restrict__ off) {
  int b = blockIdx.z;
  int i = blockIdx.x * 256 + threadIdx.x;
  int oc = i / HW;
  const float* p = offp + (size_t)b * OFFPSTRIDE + i;
  float s = ob[oc];
#pragma unroll
  for (int j = 0; j < 8; ++j) s += p[(size_t)j * (OFFC * HW)];
  off[(size_t)b * OFFSTRIDE + i] = s;
}

// ---------------- bilinear tables ----------------
__global__ void k_table(const float* __restrict__ off, int4* __restrict__ tabi,
                        float4* __restrict__ tabw) {
  int b = blockIdx.z, k = blockIdx.y;
  int px = blockIdx.x * 256 + threadIdx.x;
  const float* ob = off + (size_t)b * OFFSTRIDE;
  float dy = ob[(size_t)(2 * k) * HW + px];
  float dx = ob[(size_t)(2 * k + 1) * HW + px];
  int h = px / WIDTH, w = px - h * WIDTH;
  float py = (float)(h - 1 + k / 3) + dy;
  float pxx = (float)(w - 1 + k % 3) + dx;
  float y0 = floorf(py), x0 = floorf(pxx);
  float ay = py - y0, ax = pxx - x0;
  float wy[2] = {1.f - ay, ay}, wx[2] = {1.f - ax, ax};
  int idx[4]; float wt[4];
#pragma unroll
  for (int t = 0; t < 4; ++t) {
    float oy = y0 + (float)(t >> 1);
    float ox = x0 + (float)(t & 1);
    bool valid = (oy >= 0.f) && (oy <= 95.f) && (ox >= 0.f) && (ox <= 95.f);
    int yi = (int)fminf(fmaxf(oy, 0.f), 95.f);
    int xi = (int)fminf(fmaxf(ox, 0.f), 95.f);
    idx[t] = yi * WIDTH + xi;
    wt[t] = valid ? wy[t >> 1] * wx[t & 1] : 0.f;
  }
  size_t e = (size_t)b * TABSTRIDE + (size_t)k * HW + px;
  tabi[e] = make_int4(idx[0], idx[1], idx[2], idx[3]);
  tabw[e] = make_float4(wt[0], wt[1], wt[2], wt[3]);
}

// ---------------- sampled, transposed+bf16: samp[px][kloc*C+c] -----------
// grid: (HW/64, C/64, 6)  z: b = z&1, kloc = z>>1 ; k = chunk*3+kloc
__global__ void __launch_bounds__(256) k_sample_t(
    const float* __restrict__ xA, const float* __restrict__ xB,
    const int4* __restrict__ tabi, const float4* __restrict__ tabw,
    unsigned short* __restrict__ samp, int C, int chunk) {
  const int z = blockIdx.z;
  const int b = z & 1, kloc = z >> 1;
  const int k = chunk * 3 + kloc;
  const int t = threadIdx.x;
  const int px = blockIdx.x * 64 + (t >> 2);
  const int c0 = blockIdx.y * 64 + (t & 3) * 16;
  const float* x = b ? xB : xA;
  size_t e = (size_t)b * TABSTRIDE + (size_t)k * HW + px;
  int4 id = tabi[e];
  float4 wt = tabw[e];
  const int rowK = 3 * C;
  u16x8 o0, o1;
#pragma unroll
  for (int cc = 0; cc < 8; ++cc) {
    const float* xc = x + (size_t)(c0 + cc) * HW;
    o0[cc] = f2bf(wt.x * xc[id.x] + wt.y * xc[id.y] + wt.z * xc[id.z] + wt.w * xc[id.w]);
  }
#pragma unroll
  for (int cc = 0; cc < 8; ++cc) {
    const float* xc = x + (size_t)(c0 + 8 + cc) * HW;
    o1[cc] = f2bf(wt.x * xc[id.x] + wt.y * xc[id.y] + wt.z * xc[id.z] + wt.w * xc[id.w]);
  }
  unsigned short* dst = samp + (size_t)b * HW * rowK + (size_t)px * rowK + kloc * C + c0;
  *(u16x8*)dst = o0;
  *(u16x8*)(dst + 8) = o1;
}

// ---------------- weight prep: Ap[m][k*C+c] = dw[m][c][k] (bf16) ----------
__global__ void k_prepA(const float* __restrict__ dw, unsigned short* __restrict__ Ap,
                        int C) {
  int o = blockIdx.x * 256 + threadIdx.x;
  int K = 9 * C;
  int m = o / K, r = o - m * K;
  int k = r / C, c = r - k * C;
  Ap[o] = f2bf(dw[((size_t)m * C + c) * 9 + k]);
}

// ---------------- bf16 MFMA GEMM: Y[m][px] (+)= Ap[m][:]*samp[px][:]^T ----
// grid: (72, M/128, 2); 256 threads; m97 structure (128x128 tile, BK=32)
__global__ void __launch_bounds__(256) k_dcgemm(
    const unsigned short* __restrict__ Ap, const unsigned short* __restrict__ Bt,
    float* __restrict__ Y, int C, int chunk) {
  __shared__ unsigned short As[128 * 32];
  __shared__ unsigned short Bs[128 * 32];
  const int Kc = 3 * C;
  const int lda = 9 * C;
  const int tid = threadIdx.x;
  const int lane = tid & 63, wv = tid >> 6;
  const int b = blockIdx.z;
  const int m0 = blockIdx.y << 7, n0 = blockIdx.x << 7;
  const unsigned short* Ag = Ap + (size_t)m0 * lda + (size_t)chunk * Kc;
  const unsigned short* Bg = Bt + (size_t)b * HW * Kc + (size_t)n0 * Kc;

  const int sr0 = wv * 32 + (lane >> 2);   // staging rows (this wave's 2 LDS KB-chunks)
  const int cb = (lane & 3) * 8;           // staging col (elements)

  const int wr = wv >> 1, wc = wv & 1;     // wave quadrant (64x64)
  const int fr = lane & 15;
  const int kfo = (lane >> 4) * 8;

  f32x4 acc[4][4];
#pragma unroll
  for (int i = 0; i < 4; ++i)
#pragma unroll
    for (int j = 0; j < 4; ++j) acc[i][j] = (f32x4){0.f, 0.f, 0.f, 0.f};

  for (int kt = 0; kt < Kc; kt += 32) {
    GLDS(Ag + (size_t)sr0 * lda + kt + cb,        (char*)As + (wv * 2 + 0) * 1024);
    GLDS(Ag + (size_t)(sr0 + 16) * lda + kt + cb, (char*)As + (wv * 2 + 1) * 1024);
    GLDS(Bg + (size_t)sr0 * Kc + kt + cb,         (char*)Bs + (wv * 2 + 0) * 1024);
    GLDS(Bg + (size_t)(sr0 + 16) * Kc + kt + cb,  (char*)Bs + (wv * 2 + 1) * 1024);
    asm volatile("s_waitcnt vmcnt(0)" ::: "memory");
    __syncthreads();
    bf16x8 a[4], bb[4];
#pragma unroll
    for (int i = 0; i < 4; ++i)
      a[i] = *(const bf16x8*)&As[(wr * 64 + i * 16 + fr) * 32 + kfo];
#pragma unroll
    for (int j = 0; j < 4; ++j)
      bb[j] = *(const bf16x8*)&Bs[(wc * 64 + j * 16 + fr) * 32 + kfo];
#pragma unroll
    for (int i = 0; i < 4; ++i)
#pragma unroll
      for (int j = 0; j < 4; ++j)
        acc[i][j] = __builtin_amdgcn_mfma_f32_16x16x32_bf16(a[i], bb[j], acc[i][j], 0, 0, 0);
    __syncthreads();
  }

  float* Yb = Y + (size_t)b * FSTRIDE;
  const int orow = m0 + wr * 64 + (lane >> 4) * 4;
  const int ocol = n0 + wc * 64 + (lane & 15);
#pragma unroll
  for (int i = 0; i < 4; ++i) {
#pragma unroll
    for (int j = 0; j < 4; ++j) {
      float* p = Yb + (size_t)(orow + i * 16) * HW + ocol + j * 16;
#pragma unroll
      for (int q = 0; q < 4; ++q) {
        float v = acc[i][j][q];
        if (chunk) v += p[(size_t)q * HW];
        p[(size_t)q * HW] = v;
      }
    }
  }
}

// ---------------- GroupNorm stats ----------------
__global__ void k_gnstats(const float* __restrict__ y, float2* __restrict__ stat, int CperG) {
  int b = blockIdx.z, g = blockIdx.x;
  const float* p = y + (size_t)b * FSTRIDE + (size_t)g * CperG * HW;
  int n = CperG * HW;
  float s = 0.f, q = 0.f;
  for (int i = threadIdx.x; i < n; i += 256) { float v = p[i]; s += v; q += v * v; }
  __shared__ float ss[256], qs[256];
  ss[threadIdx.x] = s; qs[threadIdx.x] = q;
  __syncthreads();
  for (int d = 128; d > 0; d >>= 1) {
    if (threadIdx.x < d) { ss[threadIdx.x] += ss[threadIdx.x + d]; qs[threadIdx.x] += qs[threadIdx.x + d]; }
    __syncthreads();
  }
  if (threadIdx.x == 0) {
    float m = ss[0] / n;
    float var = qs[0] / n - m * m;
    stat[b * 32 + g] = make_float2(m, rsqrtf(var + 1e-5f));
  }
}

// ---------------- GroupNorm apply + ReLU ----------------
__global__ void k_gnapply(const float* __restrict__ y, const float2* __restrict__ stat,
                          const float* __restrict__ gamma, const float* __restrict__ beta,
                          float* __restrict__ out, int CperG, size_t ostride) {
  int b = blockIdx.z;
  int i = blockIdx.x * 256 + threadIdx.x;
  int c = i / HW;
  float2 st = stat[b * 32 + c / CperG];
  float v = y[(size_t)b * FSTRIDE + i];
  v = (v - st.x) * st.y * gamma[c] + beta[c];
  out[(size_t)b * ostride + i] = fmaxf(v, 0.f);
}

// ---------------- cosine-sim softmax weight (res stride 2*RSTRIDE) --------
__global__ void k_cos(const float* __restrict__ res, float* __restrict__ wpix) {
  int px = blockIdx.x * 256 + threadIdx.x;
  float saa = 0.f, sbb = 0.f, sab = 0.f;
  for (int c = 0; c < 256; ++c) {
    float a = res[(size_t)c * HW + px];
    float bb = res[2 * (size_t)RSTRIDE + (size_t)c * HW + px];
    saa += a * a; sbb += bb * bb; sab += a * bb;
  }
  float na = sqrtf(saa), nb = sqrtf(sbb);
  float ttw = saa / fmaxf(na * na, 1e-8f);
  float tkw = sab / fmaxf(na * nb, 1e-8f);
  float m = fmaxf(ttw, tkw);
  float e0 = expf(ttw - m), e1 = expf(tkw - m);
  wpix[px] = e0 / (e0 + e1);
}

// ---------------- final blend ----------------
__global__ void k_combine(const float* __restrict__ res, const float* __restrict__ wpix,
                          float* __restrict__ out) {
  int i = blockIdx.x * 256 + threadIdx.x;
  int px = i % HW;
  float w0 = wpix[px];
  out[i] = w0 * res[i] + (1.f - w0) * res[2 * (size_t)RSTRIDE + i];
}

extern "C" void kernel_launch(void* const* d_in, const int* in_sizes, int n_in,
                              void* d_out, int out_size, void* d_ws, size_t ws_size,
                              hipStream_t stream) {
  const float* datas = (const float*)d_in[0];
  const float* ow[4] = {(const float*)d_in[1], (const float*)d_in[6],
                        (const float*)d_in[11], (const float*)d_in[16]};
  const float* ob[4] = {(const float*)d_in[2], (const float*)d_in[7],
                        (const float*)d_in[12], (const float*)d_in[17]};
  const float* dw[4] = {(const float*)d_in[3], (const float*)d_in[8],
                        (const float*)d_in[13], (const float*)d_in[18]};
  const float* gg[4] = {(const float*)d_in[4], (const float*)d_in[9],
                        (const float*)d_in[14], (const float*)d_in[19]};
  const float* gb[4] = {(const float*)d_in[5], (const float*)d_in[10],
                        (const float*)d_in[15], (const float*)d_in[20]};

  float* ws = (float*)d_ws;
  float* f    = ws;                                      // 2*FSTRIDE
  float* y    = f + 2 * (size_t)FSTRIDE;                 // 2*FSTRIDE
  float* off  = y + 2 * (size_t)FSTRIDE;                 // 2*OFFSTRIDE
  float4* tabw = (float4*)(off + 2 * (size_t)OFFSTRIDE); // 2*TABSTRIDE f4
  int4*   tabi = (int4*)(tabw + 2 * (size_t)TABSTRIDE);  // 2*TABSTRIDE i4
  float* wpix = (float*)(tabi + 2 * (size_t)TABSTRIDE);  // HW
  float2* stat = (float2*)(wpix + HW);                   // 64 float2
  size_t ofs = (size_t)((wpix + HW + 128) - ws);
  ofs = (ofs + 3) & ~(size_t)3;                          // 16B align
  unsigned short* samp = (unsigned short*)(ws + ofs);    // 2*HW*1536 ushorts (56.6MB)
  float* offp = (float*)samp;                            // aliased (dead before samp written)
  unsigned short* Ap = samp + 2 * (size_t)HW * 1536;     // 512*4608 ushorts (4.7MB)

  dim3 blk(256);
  k_concat<<<dim3(FSTRIDE / 256, 1, 2), blk, 0, stream>>>(datas, f);

  for (int l = 0; l < 4; ++l) {
    const int Cx = (l < 3) ? 512 : 256;
    const int M  = (l < 3) ? 512 : 256;
    k_prepA<<<dim3(M * 9 * Cx / 256), blk, 0, stream>>>(dw[l], Ap, Cx);
    k_offconv<<<dim3(36, 8, 2), blk, 0, stream>>>(f, ow[l], offp);
    k_offreduce<<<dim3(OFFC * HW / 256, 1, 2), blk, 0, stream>>>(offp, ob[l], off);
    k_table<<<dim3(36, 9, 2), blk, 0, stream>>>(off, tabi, tabw);
    const float* xA = (l < 3) ? f : (datas + RSTRIDE);           // b0 (tt)
    const float* xB = (l < 3) ? (f + (size_t)FSTRIDE) : datas;   // b1 (tk)
    for (int ch = 0; ch < 3; ++ch) {
      k_sample_t<<<dim3(144, Cx / 64, 6), blk, 0, stream>>>(xA, xB, tabi, tabw, samp, Cx, ch);
      k_dcgemm<<<dim3(72, M / 128, 2), blk, 0, stream>>>(Ap, samp, y, Cx, ch);
    }
    k_gnstats<<<dim3(32, 1, 2), blk, 0, stream>>>(y, stat, Cx / 32);
    if (l < 3) {
      k_gnapply<<<dim3(Cx * HW / 256, 1, 2), blk, 0, stream>>>(y, stat, gg[l], gb[l], f,
                                                               Cx / 32, (size_t)FSTRIDE);
    } else {
      k_gnapply<<<dim3(Cx * HW / 256, 1, 2), blk, 0, stream>>>(y, stat, gg[l], gb[l],
                                                               y + RSTRIDE, Cx / 32,
                                                               2 * (size_t)RSTRIDE);
    }
  }

  float* res = y + RSTRIDE;  // b-stride 2*RSTRIDE (lives in y's free quadrants)
  k_cos<<<dim3(HW / 256), blk, 0, stream>>>(res, wpix);
  k_combine<<<dim3(RSTRIDE / 256), blk, 0, stream>>>(res, wpix, (float*)d_out);
}

// Round 3
// 2245.555 us; speedup vs baseline: 3.7214x; 1.2422x over previous
//
#include <hip/hip_runtime.h>
#include <math.h>

#define HW 9216
#define WIDTH 96
#define OFFC 18
#define FSTRIDE (512*HW)          // 4718592
#define RSTRIDE (256*HW)          // 2359296
#define OFFSTRIDE (OFFC*HW)       // 165888
#define OFFPSTRIDE (8*OFFC*HW)    // 1327104
#define TABSTRIDE (9*HW)          // 82944

typedef __attribute__((ext_vector_type(8))) short bf16x8;
typedef __attribute__((ext_vector_type(4))) float f32x4;
typedef __attribute__((ext_vector_type(8))) unsigned short u16x8;

__device__ __forceinline__ unsigned short f2bf(float f) {
  unsigned int u = __float_as_uint(f);
  u += 0x7FFFu + ((u >> 16) & 1u);   // RNE
  return (unsigned short)(u >> 16);
}

#define GLDS(g, l) __builtin_amdgcn_global_load_lds( \
    (const __attribute__((address_space(1))) unsigned int*)(g), \
    (__attribute__((address_space(3))) unsigned int*)(l), 16, 0, 0)

// ---------------- concat: f[b] = [sup_or_ref, ref] (float4) ----------------
__global__ void k_concat(const float* __restrict__ datas, float* __restrict__ f) {
  int b = blockIdx.z;
  int i = (blockIdx.x * 256 + threadIdx.x) * 4;
  const float* lo = datas + (size_t)(1 - b) * RSTRIDE;
  const float* hi = datas + RSTRIDE;
  float4 v = (i < RSTRIDE) ? *(const float4*)(lo + i) : *(const float4*)(hi + i - RSTRIDE);
  *(float4*)(f + (size_t)b * FSTRIDE + i) = v;
}

// ---------------- offset conv 3x3, 512 -> 18 (partial over 64-c chunk) ----
__global__ void __launch_bounds__(256) k_offconv(const float* __restrict__ f,
                                                 const float* __restrict__ ow,
                                                 float* __restrict__ offp) {
  __shared__ __align__(16) float ws_[64][168];
  const int tid = threadIdx.x;
  const int b = blockIdx.z;
  const int c0 = blockIdx.y * 64;

  for (int oc = 0; oc < OFFC; ++oc) {
    const float* src = ow + (size_t)oc * (512 * 9) + (size_t)c0 * 9;
    for (int j = tid; j < 576; j += 256)
      ws_[j / 9][oc * 9 + (j % 9)] = src[j];
  }
  __syncthreads();

  const int px = blockIdx.x * 256 + tid;
  const int h = px / WIDTH, w = px - h * WIDTH;
  const float* fb = f + (size_t)b * FSTRIDE;
  float acc[18];
#pragma unroll
  for (int i = 0; i < 18; ++i) acc[i] = 0.f;

  for (int cc = 0; cc < 64; ++cc) {
    const float* xb = fb + (size_t)(c0 + cc) * HW;
    float v[9];
#pragma unroll
    for (int r = 0; r < 3; ++r) {
      int hh = h + r - 1;
      bool rv = (hh >= 0) && (hh < 96);
#pragma unroll
      for (int cl = 0; cl < 3; ++cl) {
        int wwp = w + cl - 1;
        bool cv = (wwp >= 0) && (wwp < 96);
        v[r * 3 + cl] = (rv && cv) ? xb[hh * WIDTH + wwp] : 0.f;
      }
    }
    const float4* wrow = (const float4*)(&ws_[cc][0]);
#pragma unroll
    for (int q = 0; q < 40; ++q) {
      float4 wv = wrow[q];
      acc[(q * 4 + 0) / 9] += v[(q * 4 + 0) % 9] * wv.x;
      acc[(q * 4 + 1) / 9] += v[(q * 4 + 1) % 9] * wv.y;
      acc[(q * 4 + 2) / 9] += v[(q * 4 + 2) % 9] * wv.z;
      acc[(q * 4 + 3) / 9] += v[(q * 4 + 3) % 9] * wv.w;
    }
    acc[17] += v[7] * ws_[cc][160] + v[8] * ws_[cc][161];
  }

  float* dst = offp + (size_t)b * OFFPSTRIDE + (size_t)blockIdx.y * (OFFC * HW) + px;
#pragma unroll
  for (int oc = 0; oc < 18; ++oc) dst[(size_t)oc * HW] = acc[oc];
}

// ---------------- reduce 8 partials + bias ----------------
__global__ void k_offreduce(const float* __restrict__ offp, const float* __restrict__ ob,
                            float* __restrict__ off) {
  int b = blockIdx.z;
  int i = blockIdx.x * 256 + threadIdx.x;
  int oc = i / HW;
  const float* p = offp + (size_t)b * OFFPSTRIDE + i;
  float s = ob[oc];
#pragma unroll
  for (int j = 0; j < 8; ++j) s += p[(size_t)j * (OFFC * HW)];
  off[(size_t)b * OFFSTRIDE + i] = s;
}

// ---------------- bilinear tables ----------------
__global__ void k_table(const float* __restrict__ off, int4* __restrict__ tabi,
                        float4* __restrict__ tabw) {
  int b = blockIdx.z, k = blockIdx.y;
  int px = blockIdx.x * 256 + threadIdx.x;
  const float* ob = off + (size_t)b * OFFSTRIDE;
  float dy = ob[(size_t)(2 * k) * HW + px];
  float dx = ob[(size_t)(2 * k + 1) * HW + px];
  int h = px / WIDTH, w = px - h * WIDTH;
  float py = (float)(h - 1 + k / 3) + dy;
  float pxx = (float)(w - 1 + k % 3) + dx;
  float y0 = floorf(py), x0 = floorf(pxx);
  float ay = py - y0, ax = pxx - x0;
  float wy[2] = {1.f - ay, ay}, wx[2] = {1.f - ax, ax};
  int idx[4]; float wt[4];
#pragma unroll
  for (int t = 0; t < 4; ++t) {
    float oy = y0 + (float)(t >> 1);
    float ox = x0 + (float)(t & 1);
    bool valid = (oy >= 0.f) && (oy <= 95.f) && (ox >= 0.f) && (ox <= 95.f);
    int yi = (int)fminf(fmaxf(oy, 0.f), 95.f);
    int xi = (int)fminf(fmaxf(ox, 0.f), 95.f);
    idx[t] = yi * WIDTH + xi;
    wt[t] = valid ? wy[t >> 1] * wx[t & 1] : 0.f;
  }
  size_t e = (size_t)b * TABSTRIDE + (size_t)k * HW + px;
  tabi[e] = make_int4(idx[0], idx[1], idx[2], idx[3]);
  tabw[e] = make_float4(wt[0], wt[1], wt[2], wt[3]);
}

// ---------------- sampled, transposed+bf16: samp[px][kloc*C+c] -----------
__global__ void __launch_bounds__(256) k_sample_t(
    const float* __restrict__ xA, const float* __restrict__ xB,
    const int4* __restrict__ tabi, const float4* __restrict__ tabw,
    unsigned short* __restrict__ samp, int C, int chunk) {
  const int z = blockIdx.z;
  const int b = z & 1, kloc = z >> 1;
  const int k = chunk * 3 + kloc;
  const int t = threadIdx.x;
  const int px = blockIdx.x * 64 + (t >> 2);
  const int c0 = blockIdx.y * 64 + (t & 3) * 16;
  const float* x = b ? xB : xA;
  size_t e = (size_t)b * TABSTRIDE + (size_t)k * HW + px;
  int4 id = tabi[e];
  float4 wt = tabw[e];
  const int rowK = 3 * C;
  u16x8 o0, o1;
#pragma unroll
  for (int cc = 0; cc < 8; ++cc) {
    const float* xc = x + (size_t)(c0 + cc) * HW;
    o0[cc] = f2bf(wt.x * xc[id.x] + wt.y * xc[id.y] + wt.z * xc[id.z] + wt.w * xc[id.w]);
  }
#pragma unroll
  for (int cc = 0; cc < 8; ++cc) {
    const float* xc = x + (size_t)(c0 + 8 + cc) * HW;
    o1[cc] = f2bf(wt.x * xc[id.x] + wt.y * xc[id.y] + wt.z * xc[id.z] + wt.w * xc[id.w]);
  }
  unsigned short* dst = samp + (size_t)b * HW * rowK + (size_t)px * rowK + kloc * C + c0;
  *(u16x8*)dst = o0;
  *(u16x8*)(dst + 8) = o1;
}

// ---------------- weight prep: Ap[m][k*C+c] = dw[m][c][k] (bf16) ----------
__global__ void k_prepA(const float* __restrict__ dw, unsigned short* __restrict__ Ap,
                        int C) {
  int o = blockIdx.x * 256 + threadIdx.x;
  int K = 9 * C;
  int m = o / K, r = o - m * K;
  int k = r / C, c = r - k * C;
  Ap[o] = f2bf(dw[((size_t)m * C + c) * 9 + k]);
}

// ---------------- bf16 MFMA GEMM ----------------
__global__ void __launch_bounds__(256) k_dcgemm(
    const unsigned short* __restrict__ Ap, const unsigned short* __restrict__ Bt,
    float* __restrict__ Y, int C, int chunk) {
  __shared__ unsigned short As[128 * 32];
  __shared__ unsigned short Bs[128 * 32];
  const int Kc = 3 * C;
  const int lda = 9 * C;
  const int tid = threadIdx.x;
  const int lane = tid & 63, wv = tid >> 6;
  const int b = blockIdx.z;
  const int m0 = blockIdx.y << 7, n0 = blockIdx.x << 7;
  const unsigned short* Ag = Ap + (size_t)m0 * lda + (size_t)chunk * Kc;
  const unsigned short* Bg = Bt + (size_t)b * HW * Kc + (size_t)n0 * Kc;

  const int sr0 = wv * 32 + (lane >> 2);
  const int cb = (lane & 3) * 8;

  const int wr = wv >> 1, wc = wv & 1;
  const int fr = lane & 15;
  const int kfo = (lane >> 4) * 8;

  f32x4 acc[4][4];
#pragma unroll
  for (int i = 0; i < 4; ++i)
#pragma unroll
    for (int j = 0; j < 4; ++j) acc[i][j] = (f32x4){0.f, 0.f, 0.f, 0.f};

  for (int kt = 0; kt < Kc; kt += 32) {
    GLDS(Ag + (size_t)sr0 * lda + kt + cb,        (char*)As + (wv * 2 + 0) * 1024);
    GLDS(Ag + (size_t)(sr0 + 16) * lda + kt + cb, (char*)As + (wv * 2 + 1) * 1024);
    GLDS(Bg + (size_t)sr0 * Kc + kt + cb,         (char*)Bs + (wv * 2 + 0) * 1024);
    GLDS(Bg + (size_t)(sr0 + 16) * Kc + kt + cb,  (char*)Bs + (wv * 2 + 1) * 1024);
    asm volatile("s_waitcnt vmcnt(0)" ::: "memory");
    __syncthreads();
    bf16x8 a[4], bb[4];
#pragma unroll
    for (int i = 0; i < 4; ++i)
      a[i] = *(const bf16x8*)&As[(wr * 64 + i * 16 + fr) * 32 + kfo];
#pragma unroll
    for (int j = 0; j < 4; ++j)
      bb[j] = *(const bf16x8*)&Bs[(wc * 64 + j * 16 + fr) * 32 + kfo];
#pragma unroll
    for (int i = 0; i < 4; ++i)
#pragma unroll
      for (int j = 0; j < 4; ++j)
        acc[i][j] = __builtin_amdgcn_mfma_f32_16x16x32_bf16(a[i], bb[j], acc[i][j], 0, 0, 0);
    __syncthreads();
  }

  float* Yb = Y + (size_t)b * FSTRIDE;
  const int orow = m0 + wr * 64 + (lane >> 4) * 4;
  const int ocol = n0 + wc * 64 + (lane & 15);
#pragma unroll
  for (int i = 0; i < 4; ++i) {
#pragma unroll
    for (int j = 0; j < 4; ++j) {
      float* p = Yb + (size_t)(orow + i * 16) * HW + ocol + j * 16;
#pragma unroll
      for (int q = 0; q < 4; ++q) {
        float v = acc[i][j][q];
        if (chunk) v += p[(size_t)q * HW];
        p[(size_t)q * HW] = v;
      }
    }
  }
}

// ---------------- GroupNorm stats: stage 1 (partial sums) ----------------
// grid (32 groups, 16 chunks, 2 b), 256 thr
__global__ void __launch_bounds__(256) k_gnstats1(const float* __restrict__ y,
                                                  float2* __restrict__ part, int CperG) {
  const int b = blockIdx.z, g = blockIdx.x, ch = blockIdx.y;
  const int n = CperG * HW;
  const int cs = n >> 4;        // chunk elems
  const int cs4 = cs >> 2;      // float4s
  const float4* p = (const float4*)(y + (size_t)b * FSTRIDE + (size_t)g * n + (size_t)ch * cs);
  float s = 0.f, q = 0.f;
  for (int i = threadIdx.x; i < cs4; i += 256) {
    float4 v = p[i];
    s += v.x + v.y + v.z + v.w;
    q += v.x * v.x + v.y * v.y + v.z * v.z + v.w * v.w;
  }
  __shared__ float ss[256], qs[256];
  ss[threadIdx.x] = s; qs[threadIdx.x] = q;
  __syncthreads();
  for (int d = 128; d > 0; d >>= 1) {
    if (threadIdx.x < d) { ss[threadIdx.x] += ss[threadIdx.x + d]; qs[threadIdx.x] += qs[threadIdx.x + d]; }
    __syncthreads();
  }
  if (threadIdx.x == 0) part[((b << 5) + g) * 16 + ch] = make_float2(ss[0], qs[0]);
}

// ---------------- GroupNorm stats: stage 2 ----------------
__global__ void k_gnfin(const float2* __restrict__ part, float2* __restrict__ stat,
                        int CperG) {
  int t = threadIdx.x;  // 0..63 = (b<<5)+g
  float s = 0.f, q = 0.f;
#pragma unroll
  for (int j = 0; j < 16; ++j) { float2 v = part[t * 16 + j]; s += v.x; q += v.y; }
  float n = (float)(CperG * HW);
  float m = s / n;
  float var = q / n - m * m;
  stat[t] = make_float2(m, rsqrtf(var + 1e-5f));
}

// ---------------- GroupNorm apply + ReLU (float4) ----------------
__global__ void k_gnapply(const float* __restrict__ y, const float2* __restrict__ stat,
                          const float* __restrict__ gamma, const float* __restrict__ beta,
                          float* __restrict__ out, int CperG, size_t ostride) {
  int b = blockIdx.z;
  int i = (blockIdx.x * 256 + threadIdx.x) * 4;
  int c = i / HW;
  float2 st = stat[b * 32 + c / CperG];
  float ga = gamma[c], be = beta[c];
  float4 v = *(const float4*)(y + (size_t)b * FSTRIDE + i);
  v.x = fmaxf((v.x - st.x) * st.y * ga + be, 0.f);
  v.y = fmaxf((v.y - st.x) * st.y * ga + be, 0.f);
  v.z = fmaxf((v.z - st.x) * st.y * ga + be, 0.f);
  v.w = fmaxf((v.w - st.x) * st.y * ga + be, 0.f);
  *(float4*)(out + (size_t)b * ostride + i) = v;
}

// ---------------- cosine-sim: stage 1 partials over 32-c chunks -----------
__global__ void k_cos1(const float* __restrict__ res, float4* __restrict__ part) {
  int px = blockIdx.x * 256 + threadIdx.x;
  int cc = blockIdx.y;  // 0..7
  float saa = 0.f, sbb = 0.f, sab = 0.f;
  for (int c = cc * 32; c < cc * 32 + 32; ++c) {
    float a = res[(size_t)c * HW + px];
    float bb = res[2 * (size_t)RSTRIDE + (size_t)c * HW + px];
    saa += a * a; sbb += bb * bb; sab += a * bb;
  }
  part[(size_t)cc * HW + px] = make_float4(saa, sbb, sab, 0.f);
}

// ---------------- cosine-sim: stage 2 -> softmax weight ----------------
__global__ void k_cos2(const float4* __restrict__ part, float* __restrict__ wpix) {
  int px = blockIdx.x * 256 + threadIdx.x;
  float saa = 0.f, sbb = 0.f, sab = 0.f;
#pragma unroll
  for (int cc = 0; cc < 8; ++cc) {
    float4 v = part[(size_t)cc * HW + px];
    saa += v.x; sbb += v.y; sab += v.z;
  }
  float na = sqrtf(saa), nb = sqrtf(sbb);
  float ttw = saa / fmaxf(na * na, 1e-8f);
  float tkw = sab / fmaxf(na * nb, 1e-8f);
  float m = fmaxf(ttw, tkw);
  float e0 = expf(ttw - m), e1 = expf(tkw - m);
  wpix[px] = e0 / (e0 + e1);
}

// ---------------- final blend ----------------
__global__ void k_combine(const float* __restrict__ res, const float* __restrict__ wpix,
                          float* __restrict__ out) {
  int i = blockIdx.x * 256 + threadIdx.x;
  int px = i % HW;
  float w0 = wpix[px];
  out[i] = w0 * res[i] + (1.f - w0) * res[2 * (size_t)RSTRIDE + i];
}

extern "C" void kernel_launch(void* const* d_in, const int* in_sizes, int n_in,
                              void* d_out, int out_size, void* d_ws, size_t ws_size,
                              hipStream_t stream) {
  const float* datas = (const float*)d_in[0];
  const float* ow[4] = {(const float*)d_in[1], (const float*)d_in[6],
                        (const float*)d_in[11], (const float*)d_in[16]};
  const float* ob[4] = {(const float*)d_in[2], (const float*)d_in[7],
                        (const float*)d_in[12], (const float*)d_in[17]};
  const float* dw[4] = {(const float*)d_in[3], (const float*)d_in[8],
                        (const float*)d_in[13], (const float*)d_in[18]};
  const float* gg[4] = {(const float*)d_in[4], (const float*)d_in[9],
                        (const float*)d_in[14], (const float*)d_in[19]};
  const float* gb[4] = {(const float*)d_in[5], (const float*)d_in[10],
                        (const float*)d_in[15], (const float*)d_in[20]};

  float* ws = (float*)d_ws;
  float* f    = ws;                                      // 2*FSTRIDE
  float* y    = f + 2 * (size_t)FSTRIDE;                 // 2*FSTRIDE
  float* off  = y + 2 * (size_t)FSTRIDE;                 // 2*OFFSTRIDE
  float4* tabw = (float4*)(off + 2 * (size_t)OFFSTRIDE); // 2*TABSTRIDE f4
  int4*   tabi = (int4*)(tabw + 2 * (size_t)TABSTRIDE);  // 2*TABSTRIDE i4
  float* wpix = (float*)(tabi + 2 * (size_t)TABSTRIDE);  // HW
  float2* stat = (float2*)(wpix + HW);                   // 64 float2
  float2* gnpart = stat + 64;                            // 1024 float2
  float4* cospart = (float4*)(gnpart + 1024);            // 8*HW float4
  float* endp = (float*)(cospart + 8 * (size_t)HW);
  size_t ofs = (size_t)(endp - ws);
  ofs = (ofs + 3) & ~(size_t)3;                          // 16B align
  unsigned short* samp = (unsigned short*)(ws + ofs);    // 56.6MB
  float* offp = (float*)samp;                            // aliased scratch
  unsigned short* Ap = samp + 2 * (size_t)HW * 1536;     // 4.7MB

  dim3 blk(256);
  k_concat<<<dim3(FSTRIDE / 1024, 1, 2), blk, 0, stream>>>(datas, f);

  for (int l = 0; l < 4; ++l) {
    const int Cx = (l < 3) ? 512 : 256;
    const int M  = (l < 3) ? 512 : 256;
    k_prepA<<<dim3(M * 9 * Cx / 256), blk, 0, stream>>>(dw[l], Ap, Cx);
    k_offconv<<<dim3(36, 8, 2), blk, 0, stream>>>(f, ow[l], offp);
    k_offreduce<<<dim3(OFFC * HW / 256, 1, 2), blk, 0, stream>>>(offp, ob[l], off);
    k_table<<<dim3(36, 9, 2), blk, 0, stream>>>(off, tabi, tabw);
    const float* xA = (l < 3) ? f : (datas + RSTRIDE);           // b0 (tt)
    const float* xB = (l < 3) ? (f + (size_t)FSTRIDE) : datas;   // b1 (tk)
    for (int ch = 0; ch < 3; ++ch) {
      k_sample_t<<<dim3(144, Cx / 64, 6), blk, 0, stream>>>(xA, xB, tabi, tabw, samp, Cx, ch);
      k_dcgemm<<<dim3(72, M / 128, 2), blk, 0, stream>>>(Ap, samp, y, Cx, ch);
    }
    k_gnstats1<<<dim3(32, 16, 2), blk, 0, stream>>>(y, gnpart, Cx / 32);
    k_gnfin<<<dim3(1), dim3(64), 0, stream>>>(gnpart, stat, Cx / 32);
    if (l < 3) {
      k_gnapply<<<dim3(Cx * HW / 1024, 1, 2), blk, 0, stream>>>(y, stat, gg[l], gb[l], f,
                                                                Cx / 32, (size_t)FSTRIDE);
    } else {
      k_gnapply<<<dim3(Cx * HW / 1024, 1, 2), blk, 0, stream>>>(y, stat, gg[l], gb[l],
                                                                y + RSTRIDE, Cx / 32,
                                                                2 * (size_t)RSTRIDE);
    }
  }

  float* res = y + RSTRIDE;  // b-stride 2*RSTRIDE
  k_cos1<<<dim3(36, 8), blk, 0, stream>>>(res, cospart);
  k_cos2<<<dim3(36), blk, 0, stream>>>(cospart, wpix);
  k_combine<<<dim3(RSTRIDE / 256), blk, 0, stream>>>(res, wpix, (float*)d_out);
}

// Round 4
// 1345.945 us; speedup vs baseline: 6.2087x; 1.6684x over previous
//
#include <hip/hip_runtime.h>
#include <math.h>

#define HW 9216
#define WIDTH 96
#define FSTRIDE (512*HW)          // 4718592
#define RSTRIDE (256*HW)          // 2359296
#define TABSTRIDE (9*HW)          // 82944
#define PXP 12544                 // 98 rows * 128
#define FTPROWS 12800             // 100 rows (guard + 98 + guard)

typedef __attribute__((ext_vector_type(8))) short bf16x8;
typedef __attribute__((ext_vector_type(4))) float f32x4;
typedef __attribute__((ext_vector_type(8))) unsigned short u16x8;

__device__ __forceinline__ unsigned short f2bf(float f) {
  unsigned int u = __float_as_uint(f);
  u += 0x7FFFu + ((u >> 16) & 1u);   // RNE
  return (unsigned short)(u >> 16);
}
__device__ __forceinline__ float bf2f(unsigned short s) {
  return __uint_as_float(((unsigned int)s) << 16);
}

#define GLDS(g, l) __builtin_amdgcn_global_load_lds( \
    (const __attribute__((address_space(1))) unsigned int*)(g), \
    (__attribute__((address_space(3))) unsigned int*)(l), 16, 0, 0)

// ---------------- zero helper (u16x8 granules) ----------------
__global__ void k_zero(unsigned short* p, unsigned int n8) {
  unsigned int i = blockIdx.x * 256 + threadIdx.x;
  if (i < n8) ((u16x8*)p)[i] = (u16x8){0, 0, 0, 0, 0, 0, 0, 0};
}

// ---------------- concat: f[b] = [sup_or_ref, ref] (float4) ----------------
__global__ void k_concat(const float* __restrict__ datas, float* __restrict__ f) {
  int b = blockIdx.z;
  int i = (blockIdx.x * 256 + threadIdx.x) * 4;
  const float* lo = datas + (size_t)(1 - b) * RSTRIDE;
  const float* hi = datas + RSTRIDE;
  float4 v = (i < RSTRIDE) ? *(const float4*)(lo + i) : *(const float4*)(hi + i - RSTRIDE);
  *(float4*)(f + (size_t)b * FSTRIDE + i) = v;
}

// ---------------- ftp builder: src fp32 [C][HW] -> padded bf16 [pxp][C] ----
// grid (144, C/64, 2)
__global__ void __launch_bounds__(256) k_mkftp(const float* __restrict__ srcA,
                                               const float* __restrict__ srcB,
                                               unsigned short* __restrict__ dst,
                                               int C) {
  const int b = blockIdx.z;
  const float* src = b ? srcB : srcA;
  unsigned short* d = dst + (size_t)b * FTPROWS * C + 128 * C;  // skip guard row
  const int px0 = blockIdx.x * 64, c0 = blockIdx.y * 64;
  __shared__ float tile[64][65];
  const int t = threadIdx.x;
#pragma unroll
  for (int rep = 0; rep < 16; ++rep) {
    int idx = rep * 256 + t;
    int cl = idx >> 6, pl = idx & 63;
    tile[cl][pl] = src[(size_t)(c0 + cl) * HW + px0 + pl];
  }
  __syncthreads();
  const int pl = t >> 2, cu = (t & 3) * 16;
  const int px = px0 + pl;
  const int h = px / WIDTH, w = px - h * WIDTH;
  const size_t pxp = (size_t)(h + 1) * 128 + (w + 1);
  u16x8 o0, o1;
#pragma unroll
  for (int j = 0; j < 8; ++j) o0[j] = f2bf(tile[cu + j][pl]);
#pragma unroll
  for (int j = 0; j < 8; ++j) o1[j] = f2bf(tile[cu + 8 + j][pl]);
  unsigned short* p = d + pxp * C + c0 + cu;
  *(u16x8*)p = o0;
  *(u16x8*)(p + 8) = o1;
}

// ---------------- offconv weights: Wt[k][oc(32 pad)][c] bf16 ----------------
__global__ void k_prepW(const float* __restrict__ ow, unsigned short* __restrict__ Wt) {
  int i = blockIdx.x * 256 + threadIdx.x;  // < 9*32*512
  int k = i / (32 * 512), r = i - k * 32 * 512;
  int oc = r / 512, c = r - oc * 512;
  Wt[i] = (oc < 18) ? f2bf(ow[((size_t)oc * 512 + c) * 9 + k]) : (unsigned short)0;
}

// ---------------- offset conv via MFMA: part[b][ks][pxp][32] ----------------
// grid (96, 3, 2), 256 thr. A = ftp rows (shifted), B = Wt[k]. C always 512.
__global__ void __launch_bounds__(256) k_offmm(const unsigned short* __restrict__ ftp,
                                               const unsigned short* __restrict__ Wt,
                                               float* __restrict__ part) {
  const int C = 512;
  __shared__ unsigned short As[128 * 64];  // 16 KB, row stride 128B, XOR-swizzled
  __shared__ unsigned short Bs[32 * 64];   // 4 KB
  const int tid = threadIdx.x;
  const int lane = tid & 63, wv = tid >> 6;
  const int b = blockIdx.z, ks = blockIdx.y;
  const int pxp0 = 128 + blockIdx.x * 128;
  const unsigned short* fb = ftp + (size_t)b * FTPROWS * C + 128 * C;  // valid row 0

  const int lr = lane >> 3;            // staging row-in-group
  const int lu = lane & 7;             // staging 16B-unit
  const int fr = lane & 15, hi = lane >> 4;

  f32x4 acc[2][2];
#pragma unroll
  for (int i = 0; i < 2; ++i)
#pragma unroll
    for (int j = 0; j < 2; ++j) acc[i][j] = (f32x4){0.f, 0.f, 0.f, 0.f};

  for (int kt = 0; kt < 3; ++kt) {
    const int k = ks * 3 + kt;
    const int dlt = (k / 3 - 1) * 128 + (k % 3 - 1);
    for (int c0 = 0; c0 < C; c0 += 64) {
      // stage A: wave wv covers rows wv*32..wv*32+32 (4 GLDS of 8 rows)
#pragma unroll
      for (int q = 0; q < 4; ++q) {
        int row = wv * 32 + q * 8 + lr;
        int su = lu ^ (row & 7);  // inverse swizzle on global source
        GLDS(fb + (size_t)(pxp0 + dlt + row) * C + c0 + su * 8,
             (char*)As + (wv * 32 + q * 8) * 128);
      }
      {  // stage B: wave wv covers rows 8wv..8wv+8 of Wt[k]
        int row = wv * 8 + lr;
        int su = lu ^ (row & 7);
        GLDS(Wt + ((size_t)k * 32 + row) * C + c0 + su * 8,
             (char*)Bs + wv * 8 * 128);
      }
      asm volatile("s_waitcnt vmcnt(0)" ::: "memory");
      __syncthreads();
#pragma unroll
      for (int kk = 0; kk < 2; ++kk) {
        bf16x8 a[2], bb[2];
#pragma unroll
        for (int i = 0; i < 2; ++i) {
          int row = wv * 32 + i * 16 + fr;
          a[i] = *(const bf16x8*)&As[row * 64 + (((kk * 4 + hi) ^ (row & 7)) * 8)];
        }
#pragma unroll
        for (int j = 0; j < 2; ++j) {
          int row = j * 16 + fr;
          bb[j] = *(const bf16x8*)&Bs[row * 64 + (((kk * 4 + hi) ^ (row & 7)) * 8)];
        }
#pragma unroll
        for (int i = 0; i < 2; ++i)
#pragma unroll
          for (int j = 0; j < 2; ++j)
            acc[i][j] = __builtin_amdgcn_mfma_f32_16x16x32_bf16(a[i], bb[j], acc[i][j], 0, 0, 0);
      }
      __syncthreads();
    }
  }

  float* pb = part + ((size_t)(b * 3 + ks)) * PXP * 32;
#pragma unroll
  for (int i = 0; i < 2; ++i)
#pragma unroll
    for (int j = 0; j < 2; ++j) {
      int row0 = pxp0 + wv * 32 + i * 16 + hi * 4;
      int col = j * 16 + fr;
#pragma unroll
      for (int q = 0; q < 4; ++q)
        pb[(size_t)(row0 + q) * 32 + col] = acc[i][j][q];
    }
}

// ---------------- bilinear tables (padded ids; sums 3 partials + bias) -----
__global__ void k_table(const float* __restrict__ part, const float* __restrict__ ob,
                        int4* __restrict__ tabi, float4* __restrict__ tabw) {
  int b = blockIdx.z, k = blockIdx.y;
  int px = blockIdx.x * 256 + threadIdx.x;
  int h = px / WIDTH, w = px - h * WIDTH;
  size_t pxp = (size_t)(h + 1) * 128 + (w + 1);
  const float* pb = part + (size_t)b * 3 * PXP * 32 + pxp * 32;
  float dy = ob[2 * k] + pb[2 * k] + pb[(size_t)PXP * 32 + 2 * k] + pb[2 * (size_t)PXP * 32 + 2 * k];
  float dx = ob[2 * k + 1] + pb[2 * k + 1] + pb[(size_t)PXP * 32 + 2 * k + 1] + pb[2 * (size_t)PXP * 32 + 2 * k + 1];
  float py = (float)(h - 1 + k / 3) + dy;
  float pxx = (float)(w - 1 + k % 3) + dx;
  float y0 = floorf(py), x0 = floorf(pxx);
  float ay = py - y0, ax = pxx - x0;
  float wy[2] = {1.f - ay, ay}, wx[2] = {1.f - ax, ax};
  int idx[4]; float wt[4];
#pragma unroll
  for (int t = 0; t < 4; ++t) {
    float oy = y0 + (float)(t >> 1);
    float ox = x0 + (float)(t & 1);
    bool valid = (oy >= 0.f) && (oy <= 95.f) && (ox >= 0.f) && (ox <= 95.f);
    int yi = (int)fminf(fmaxf(oy, 0.f), 95.f);
    int xi = (int)fminf(fmaxf(ox, 0.f), 95.f);
    idx[t] = (yi + 1) * 128 + (xi + 1);   // padded id
    wt[t] = valid ? wy[t >> 1] * wx[t & 1] : 0.f;
  }
  size_t e = (size_t)b * TABSTRIDE + (size_t)k * HW + px;
  tabi[e] = make_int4(idx[0], idx[1], idx[2], idx[3]);
  tabw[e] = make_float4(wt[0], wt[1], wt[2], wt[3]);
}

// ---------------- sampled from ftp (bf16 gather): samp[px][kloc*C+c] -------
// grid (144, C/64, 6)  z: b = z&1, kloc = z>>1
__global__ void __launch_bounds__(256) k_sample_t(
    const unsigned short* __restrict__ ftp,
    const int4* __restrict__ tabi, const float4* __restrict__ tabw,
    unsigned short* __restrict__ samp, int C, int chunk) {
  const int z = blockIdx.z;
  const int b = z & 1, kloc = z >> 1;
  const int k = chunk * 3 + kloc;
  const int t = threadIdx.x;
  const int px = blockIdx.x * 64 + (t >> 2);
  const int c = blockIdx.y * 64 + (t & 3) * 16;
  const unsigned short* fb = ftp + (size_t)b * FTPROWS * C + 128 * C;
  size_t e = (size_t)b * TABSTRIDE + (size_t)k * HW + px;
  int4 id = tabi[e];
  float4 wt = tabw[e];
  float acc[16];
#pragma unroll
  for (int j = 0; j < 16; ++j) acc[j] = 0.f;
  const int ids[4] = {id.x, id.y, id.z, id.w};
  const float wts[4] = {wt.x, wt.y, wt.z, wt.w};
#pragma unroll
  for (int s = 0; s < 4; ++s) {
    const unsigned short* p = fb + (size_t)ids[s] * C + c;
    u16x8 v0 = *(const u16x8*)p;
    u16x8 v1 = *(const u16x8*)(p + 8);
    float wgt = wts[s];
#pragma unroll
    for (int j = 0; j < 8; ++j) acc[j] += wgt * bf2f(v0[j]);
#pragma unroll
    for (int j = 0; j < 8; ++j) acc[8 + j] += wgt * bf2f(v1[j]);
  }
  u16x8 o0, o1;
#pragma unroll
  for (int j = 0; j < 8; ++j) o0[j] = f2bf(acc[j]);
#pragma unroll
  for (int j = 0; j < 8; ++j) o1[j] = f2bf(acc[8 + j]);
  const int rowK = 3 * C;
  unsigned short* dst = samp + (size_t)b * HW * rowK + (size_t)px * rowK + kloc * C + c;
  *(u16x8*)dst = o0;
  *(u16x8*)(dst + 8) = o1;
}

// ---------------- weight prep: Ap[m][k*C+c] = dw[m][c][k] (bf16) ----------
__global__ void k_prepA(const float* __restrict__ dw, unsigned short* __restrict__ Ap,
                        int C) {
  int o = blockIdx.x * 256 + threadIdx.x;
  int K = 9 * C;
  int m = o / K, r = o - m * K;
  int k = r / C, c = r - k * C;
  Ap[o] = f2bf(dw[((size_t)m * C + c) * 9 + k]);
}

// ---------------- bf16 MFMA GEMM ----------------
__global__ void __launch_bounds__(256) k_dcgemm(
    const unsigned short* __restrict__ Ap, const unsigned short* __restrict__ Bt,
    float* __restrict__ Y, int C, int chunk) {
  __shared__ unsigned short As[128 * 32];
  __shared__ unsigned short Bs[128 * 32];
  const int Kc = 3 * C;
  const int lda = 9 * C;
  const int tid = threadIdx.x;
  const int lane = tid & 63, wv = tid >> 6;
  const int b = blockIdx.z;
  const int m0 = blockIdx.y << 7, n0 = blockIdx.x << 7;
  const unsigned short* Ag = Ap + (size_t)m0 * lda + (size_t)chunk * Kc;
  const unsigned short* Bg = Bt + (size_t)b * HW * Kc + (size_t)n0 * Kc;

  const int sr0 = wv * 32 + (lane >> 2);
  const int cb = (lane & 3) * 8;

  const int wr = wv >> 1, wc = wv & 1;
  const int fr = lane & 15;
  const int kfo = (lane >> 4) * 8;

  f32x4 acc[4][4];
#pragma unroll
  for (int i = 0; i < 4; ++i)
#pragma unroll
    for (int j = 0; j < 4; ++j) acc[i][j] = (f32x4){0.f, 0.f, 0.f, 0.f};

  for (int kt = 0; kt < Kc; kt += 32) {
    GLDS(Ag + (size_t)sr0 * lda + kt + cb,        (char*)As + (wv * 2 + 0) * 1024);
    GLDS(Ag + (size_t)(sr0 + 16) * lda + kt + cb, (char*)As + (wv * 2 + 1) * 1024);
    GLDS(Bg + (size_t)sr0 * Kc + kt + cb,         (char*)Bs + (wv * 2 + 0) * 1024);
    GLDS(Bg + (size_t)(sr0 + 16) * Kc + kt + cb,  (char*)Bs + (wv * 2 + 1) * 1024);
    asm volatile("s_waitcnt vmcnt(0)" ::: "memory");
    __syncthreads();
    bf16x8 a[4], bb[4];
#pragma unroll
    for (int i = 0; i < 4; ++i)
      a[i] = *(const bf16x8*)&As[(wr * 64 + i * 16 + fr) * 32 + kfo];
#pragma unroll
    for (int j = 0; j < 4; ++j)
      bb[j] = *(const bf16x8*)&Bs[(wc * 64 + j * 16 + fr) * 32 + kfo];
#pragma unroll
    for (int i = 0; i < 4; ++i)
#pragma unroll
      for (int j = 0; j < 4; ++j)
        acc[i][j] = __builtin_amdgcn_mfma_f32_16x16x32_bf16(a[i], bb[j], acc[i][j], 0, 0, 0);
    __syncthreads();
  }

  float* Yb = Y + (size_t)b * FSTRIDE;
  const int orow = m0 + wr * 64 + (lane >> 4) * 4;
  const int ocol = n0 + wc * 64 + (lane & 15);
#pragma unroll
  for (int i = 0; i < 4; ++i) {
#pragma unroll
    for (int j = 0; j < 4; ++j) {
      float* p = Yb + (size_t)(orow + i * 16) * HW + ocol + j * 16;
#pragma unroll
      for (int q = 0; q < 4; ++q) {
        float v = acc[i][j][q];
        if (chunk) v += p[(size_t)q * HW];
        p[(size_t)q * HW] = v;
      }
    }
  }
}

// ---------------- GroupNorm stats: stage 1 ----------------
__global__ void __launch_bounds__(256) k_gnstats1(const float* __restrict__ y,
                                                  float2* __restrict__ part, int CperG) {
  const int b = blockIdx.z, g = blockIdx.x, ch = blockIdx.y;
  const int n = CperG * HW;
  const int cs = n >> 4;
  const int cs4 = cs >> 2;
  const float4* p = (const float4*)(y + (size_t)b * FSTRIDE + (size_t)g * n + (size_t)ch * cs);
  float s = 0.f, q = 0.f;
  for (int i = threadIdx.x; i < cs4; i += 256) {
    float4 v = p[i];
    s += v.x + v.y + v.z + v.w;
    q += v.x * v.x + v.y * v.y + v.z * v.z + v.w * v.w;
  }
  __shared__ float ss[256], qs[256];
  ss[threadIdx.x] = s; qs[threadIdx.x] = q;
  __syncthreads();
  for (int d = 128; d > 0; d >>= 1) {
    if (threadIdx.x < d) { ss[threadIdx.x] += ss[threadIdx.x + d]; qs[threadIdx.x] += qs[threadIdx.x + d]; }
    __syncthreads();
  }
  if (threadIdx.x == 0) part[((b << 5) + g) * 16 + ch] = make_float2(ss[0], qs[0]);
}

// ---------------- GroupNorm stats: stage 2 ----------------
__global__ void k_gnfin(const float2* __restrict__ part, float2* __restrict__ stat,
                        int CperG) {
  int t = threadIdx.x;
  float s = 0.f, q = 0.f;
#pragma unroll
  for (int j = 0; j < 16; ++j) { float2 v = part[t * 16 + j]; s += v.x; q += v.y; }
  float n = (float)(CperG * HW);
  float m = s / n;
  float var = q / n - m * m;
  stat[t] = make_float2(m, rsqrtf(var + 1e-5f));
}

// ---------------- GroupNorm apply + ReLU (float4) ----------------
__global__ void k_gnapply(const float* __restrict__ y, const float2* __restrict__ stat,
                          const float* __restrict__ gamma, const float* __restrict__ beta,
                          float* __restrict__ out, int CperG, size_t ostride) {
  int b = blockIdx.z;
  int i = (blockIdx.x * 256 + threadIdx.x) * 4;
  int c = i / HW;
  float2 st = stat[b * 32 + c / CperG];
  float ga = gamma[c], be = beta[c];
  float4 v = *(const float4*)(y + (size_t)b * FSTRIDE + i);
  v.x = fmaxf((v.x - st.x) * st.y * ga + be, 0.f);
  v.y = fmaxf((v.y - st.x) * st.y * ga + be, 0.f);
  v.z = fmaxf((v.z - st.x) * st.y * ga + be, 0.f);
  v.w = fmaxf((v.w - st.x) * st.y * ga + be, 0.f);
  *(float4*)(out + (size_t)b * ostride + i) = v;
}

// ---------------- cosine-sim: stage 1 ----------------
__global__ void k_cos1(const float* __restrict__ res, float4* __restrict__ part) {
  int px = blockIdx.x * 256 + threadIdx.x;
  int cc = blockIdx.y;
  float saa = 0.f, sbb = 0.f, sab = 0.f;
  for (int c = cc * 32; c < cc * 32 + 32; ++c) {
    float a = res[(size_t)c * HW + px];
    float bb = res[2 * (size_t)RSTRIDE + (size_t)c * HW + px];
    saa += a * a; sbb += bb * bb; sab += a * bb;
  }
  part[(size_t)cc * HW + px] = make_float4(saa, sbb, sab, 0.f);
}

// ---------------- cosine-sim: stage 2 ----------------
__global__ void k_cos2(const float4* __restrict__ part, float* __restrict__ wpix) {
  int px = blockIdx.x * 256 + threadIdx.x;
  float saa = 0.f, sbb = 0.f, sab = 0.f;
#pragma unroll
  for (int cc = 0; cc < 8; ++cc) {
    float4 v = part[(size_t)cc * HW + px];
    saa += v.x; sbb += v.y; sab += v.z;
  }
  float na = sqrtf(saa), nb = sqrtf(sbb);
  float ttw = saa / fmaxf(na * na, 1e-8f);
  float tkw = sab / fmaxf(na * nb, 1e-8f);
  float m = fmaxf(ttw, tkw);
  float e0 = expf(ttw - m), e1 = expf(tkw - m);
  wpix[px] = e0 / (e0 + e1);
}

// ---------------- final blend ----------------
__global__ void k_combine(const float* __restrict__ res, const float* __restrict__ wpix,
                          float* __restrict__ out) {
  int i = blockIdx.x * 256 + threadIdx.x;
  int px = i % HW;
  float w0 = wpix[px];
  out[i] = w0 * res[i] + (1.f - w0) * res[2 * (size_t)RSTRIDE + i];
}

extern "C" void kernel_launch(void* const* d_in, const int* in_sizes, int n_in,
                              void* d_out, int out_size, void* d_ws, size_t ws_size,
                              hipStream_t stream) {
  const float* datas = (const float*)d_in[0];
  const float* ow[4] = {(const float*)d_in[1], (const float*)d_in[6],
                        (const float*)d_in[11], (const float*)d_in[16]};
  const float* ob[4] = {(const float*)d_in[2], (const float*)d_in[7],
                        (const float*)d_in[12], (const float*)d_in[17]};
  const float* dw[4] = {(const float*)d_in[3], (const float*)d_in[8],
                        (const float*)d_in[13], (const float*)d_in[18]};
  const float* gg[4] = {(const float*)d_in[4], (const float*)d_in[9],
                        (const float*)d_in[14], (const float*)d_in[19]};
  const float* gb[4] = {(const float*)d_in[5], (const float*)d_in[10],
                        (const float*)d_in[15], (const float*)d_in[20]};

  float* ws = (float*)d_ws;
  float* f    = ws;                                      // 2*FSTRIDE fp32
  float* y    = f + 2 * (size_t)FSTRIDE;                 // 2*FSTRIDE fp32
  float* offp3 = y + 2 * (size_t)FSTRIDE;                // 2*3*PXP*32 fp32 (9.6MB)
  float4* tabw = (float4*)(offp3 + 2 * 3 * (size_t)PXP * 32);
  int4*   tabi = (int4*)(tabw + 2 * (size_t)TABSTRIDE);
  float* wpix = (float*)(tabi + 2 * (size_t)TABSTRIDE);  // HW
  float2* stat = (float2*)(wpix + HW);                   // 64
  float2* gnpart = stat + 64;                            // 1024
  float4* cospart = (float4*)(gnpart + 1024);            // 8*HW
  float* endp = (float*)(cospart + 8 * (size_t)HW);
  size_t ofs = ((size_t)(endp - ws) + 3) & ~(size_t)3;
  unsigned short* samp = (unsigned short*)(ws + ofs);    // 2*HW*1536 us (56.6MB)
  unsigned short* Ap = samp + 2 * (size_t)HW * 1536;     // 512*4608 us
  unsigned short* Wt = Ap + (size_t)512 * 4608;          // 9*32*512 us
  unsigned short* ftp512 = Wt + (size_t)9 * 32 * 512;    // 2*FTPROWS*512 us (26.2MB)
  unsigned short* ftp256 = (unsigned short*)f;           // aliases f (dead at layer 4)

  dim3 blk(256);
  k_zero<<<dim3(2 * FTPROWS * 512 / 8 / 256), blk, 0, stream>>>(ftp512, 2u * FTPROWS * 512 / 8);
  k_concat<<<dim3(FSTRIDE / 1024, 1, 2), blk, 0, stream>>>(datas, f);

  for (int l = 0; l < 4; ++l) {
    const int Cx = (l < 3) ? 512 : 256;   // deform-conv channels
    const int M  = Cx;
    k_prepA<<<dim3(M * 9 * Cx / 256), blk, 0, stream>>>(dw[l], Ap, Cx);
    k_prepW<<<dim3(9 * 32 * 512 / 256), blk, 0, stream>>>(ow[l], Wt);
    // feature map for offset conv (always 512-ch f)
    k_mkftp<<<dim3(144, 8, 2), blk, 0, stream>>>(f, f + FSTRIDE, ftp512, 512);
    k_offmm<<<dim3(96, 3, 2), blk, 0, stream>>>(ftp512, Wt, offp3);
    k_table<<<dim3(36, 9, 2), blk, 0, stream>>>(offp3, ob[l], tabi, tabw);
    const unsigned short* sftp;
    if (l < 3) {
      sftp = ftp512;
    } else {
      // layer 4 samples from support/ref (256 ch); build into f's storage
      k_zero<<<dim3(2 * FTPROWS * 256 / 8 / 256), blk, 0, stream>>>(ftp256, 2u * FTPROWS * 256 / 8);
      k_mkftp<<<dim3(144, 4, 2), blk, 0, stream>>>(datas + RSTRIDE, datas, ftp256, 256);
      sftp = ftp256;
    }
    for (int ch = 0; ch < 3; ++ch) {
      k_sample_t<<<dim3(144, Cx / 64, 6), blk, 0, stream>>>(sftp, tabi, tabw, samp, Cx, ch);
      k_dcgemm<<<dim3(72, M / 128, 2), blk, 0, stream>>>(Ap, samp, y, Cx, ch);
    }
    k_gnstats1<<<dim3(32, 16, 2), blk, 0, stream>>>(y, gnpart, Cx / 32);
    k_gnfin<<<dim3(1), dim3(64), 0, stream>>>(gnpart, stat, Cx / 32);
    if (l < 3) {
      k_gnapply<<<dim3(Cx * HW / 1024, 1, 2), blk, 0, stream>>>(y, stat, gg[l], gb[l], f,
                                                                Cx / 32, (size_t)FSTRIDE);
    } else {
      k_gnapply<<<dim3(Cx * HW / 1024, 1, 2), blk, 0, stream>>>(y, stat, gg[l], gb[l],
                                                                y + RSTRIDE, Cx / 32,
                                                                2 * (size_t)RSTRIDE);
    }
  }

  float* res = y + RSTRIDE;  // b-stride 2*RSTRIDE
  k_cos1<<<dim3(36, 8), blk, 0, stream>>>(res, cospart);
  k_cos2<<<dim3(36), blk, 0, stream>>>(cospart, wpix);
  k_combine<<<dim3(RSTRIDE / 256), blk, 0, stream>>>(res, wpix, (float*)d_out);
}

// Round 5
// 1105.692 us; speedup vs baseline: 7.5577x; 1.2173x over previous
//
#include <hip/hip_runtime.h>
#include <math.h>

#define HW 9216
#define WIDTH 96
#define FSTRIDE (512*HW)          // 4718592
#define RSTRIDE (256*HW)          // 2359296
#define TABSTRIDE (9*HW)          // 82944
#define PXP 12544                 // 98 rows * 128
#define FTPROWS 12800             // 100 rows (guard + 98 + guard)

typedef __attribute__((ext_vector_type(8))) short bf16x8;
typedef __attribute__((ext_vector_type(4))) float f32x4;
typedef __attribute__((ext_vector_type(8))) unsigned short u16x8;

__device__ __forceinline__ unsigned short f2bf(float f) {
  unsigned int u = __float_as_uint(f);
  u += 0x7FFFu + ((u >> 16) & 1u);   // RNE
  return (unsigned short)(u >> 16);
}
__device__ __forceinline__ float bf2f(unsigned short s) {
  return __uint_as_float(((unsigned int)s) << 16);
}

#define GLDS(g, l) __builtin_amdgcn_global_load_lds( \
    (const __attribute__((address_space(1))) unsigned int*)(g), \
    (__attribute__((address_space(3))) unsigned int*)(l), 16, 0, 0)

// ---------------- zero helper ----------------
__global__ void k_zero(unsigned short* p, unsigned int n8) {
  unsigned int i = blockIdx.x * 256 + threadIdx.x;
  if (i < n8) ((u16x8*)p)[i] = (u16x8){0, 0, 0, 0, 0, 0, 0, 0};
}

// ---------------- ftp from concat sources: [b][pxp][C] bf16 ----------------
// c < CB comes from (b ? lo1 : lo0), c >= CB from hi (channel c-CB)
__global__ void __launch_bounds__(256) k_mkftp_cat(
    const float* __restrict__ lo0, const float* __restrict__ lo1,
    const float* __restrict__ hi, unsigned short* __restrict__ dst,
    int C, int CB) {
  const int b = blockIdx.z;
  const float* lo = b ? lo1 : lo0;
  unsigned short* d = dst + (size_t)b * FTPROWS * C + 128 * C;
  const int px0 = blockIdx.x * 64, c0 = blockIdx.y * 64;
  __shared__ float tile[64][65];
  const int t = threadIdx.x;
#pragma unroll
  for (int rep = 0; rep < 16; ++rep) {
    int idx = rep * 256 + t;
    int cl = idx >> 6, pl = idx & 63;
    int cg = c0 + cl;
    const float* s = (cg < CB) ? (lo + (size_t)cg * HW) : (hi + (size_t)(cg - CB) * HW);
    tile[cl][pl] = s[px0 + pl];
  }
  __syncthreads();
  const int pl = t >> 2, cu = (t & 3) * 16;
  const int px = px0 + pl;
  const int h = px / WIDTH, w = px - h * WIDTH;
  const size_t pxp = (size_t)(h + 1) * 128 + (w + 1);
  u16x8 o0, o1;
#pragma unroll
  for (int j = 0; j < 8; ++j) o0[j] = f2bf(tile[cu + j][pl]);
#pragma unroll
  for (int j = 0; j < 8; ++j) o1[j] = f2bf(tile[cu + 8 + j][pl]);
  unsigned short* p = d + pxp * C + c0 + cu;
  *(u16x8*)p = o0;
  *(u16x8*)(p + 8) = o1;
}

// ---------------- ftp from GN(y)+ReLU (C=512, CperG=16) ----------------
__global__ void __launch_bounds__(256) k_mkftp_gn(
    const float* __restrict__ y, const float2* __restrict__ stat,
    const float* __restrict__ gamma, const float* __restrict__ beta,
    unsigned short* __restrict__ dst) {
  const int C = 512;
  const int b = blockIdx.z;
  unsigned short* d = dst + (size_t)b * FTPROWS * C + 128 * C;
  const int px0 = blockIdx.x * 64, c0 = blockIdx.y * 64;
  __shared__ float tile[64][65];
  const int t = threadIdx.x;
#pragma unroll
  for (int rep = 0; rep < 16; ++rep) {
    int idx = rep * 256 + t;
    int cl = idx >> 6, pl = idx & 63;
    int cg = c0 + cl;
    float2 st = stat[b * 32 + (cg >> 4)];
    float v = y[(size_t)b * FSTRIDE + (size_t)cg * HW + px0 + pl];
    v = (v - st.x) * st.y * gamma[cg] + beta[cg];
    tile[cl][pl] = fmaxf(v, 0.f);
  }
  __syncthreads();
  const int pl = t >> 2, cu = (t & 3) * 16;
  const int px = px0 + pl;
  const int h = px / WIDTH, w = px - h * WIDTH;
  const size_t pxp = (size_t)(h + 1) * 128 + (w + 1);
  u16x8 o0, o1;
#pragma unroll
  for (int j = 0; j < 8; ++j) o0[j] = f2bf(tile[cu + j][pl]);
#pragma unroll
  for (int j = 0; j < 8; ++j) o1[j] = f2bf(tile[cu + 8 + j][pl]);
  unsigned short* p = d + pxp * C + c0 + cu;
  *(u16x8*)p = o0;
  *(u16x8*)(p + 8) = o1;
}

// ---------------- offconv weights: Wt[k][oc(32 pad)][c] bf16 ----------------
__global__ void k_prepW(const float* __restrict__ ow, unsigned short* __restrict__ Wt) {
  int i = blockIdx.x * 256 + threadIdx.x;  // < 9*32*512
  int k = i / (32 * 512), r = i - k * 32 * 512;
  int oc = r / 512, c = r - oc * 512;
  Wt[i] = (oc < 18) ? f2bf(ow[((size_t)oc * 512 + c) * 9 + k]) : (unsigned short)0;
}

// ---------------- offset conv via MFMA: part[b][ks][pxp][32] ----------------
__global__ void __launch_bounds__(256) k_offmm(const unsigned short* __restrict__ ftp,
                                               const unsigned short* __restrict__ Wt,
                                               float* __restrict__ part) {
  const int C = 512;
  __shared__ unsigned short As[128 * 64];
  __shared__ unsigned short Bs[32 * 64];
  const int tid = threadIdx.x;
  const int lane = tid & 63, wv = tid >> 6;
  const int b = blockIdx.z, ks = blockIdx.y;
  const int pxp0 = 128 + blockIdx.x * 128;
  const unsigned short* fb = ftp + (size_t)b * FTPROWS * C + 128 * C;

  const int lr = lane >> 3;
  const int lu = lane & 7;
  const int fr = lane & 15, hi = lane >> 4;

  f32x4 acc[2][2];
#pragma unroll
  for (int i = 0; i < 2; ++i)
#pragma unroll
    for (int j = 0; j < 2; ++j) acc[i][j] = (f32x4){0.f, 0.f, 0.f, 0.f};

  for (int kt = 0; kt < 3; ++kt) {
    const int k = ks * 3 + kt;
    const int dlt = (k / 3 - 1) * 128 + (k % 3 - 1);
    for (int c0 = 0; c0 < C; c0 += 64) {
#pragma unroll
      for (int q = 0; q < 4; ++q) {
        int row = wv * 32 + q * 8 + lr;
        int su = lu ^ (row & 7);
        GLDS(fb + (size_t)(pxp0 + dlt + row) * C + c0 + su * 8,
             (char*)As + (wv * 32 + q * 8) * 128);
      }
      {
        int row = wv * 8 + lr;
        int su = lu ^ (row & 7);
        GLDS(Wt + ((size_t)k * 32 + row) * C + c0 + su * 8,
             (char*)Bs + wv * 8 * 128);
      }
      asm volatile("s_waitcnt vmcnt(0)" ::: "memory");
      __syncthreads();
#pragma unroll
      for (int kk = 0; kk < 2; ++kk) {
        bf16x8 a[2], bb[2];
#pragma unroll
        for (int i = 0; i < 2; ++i) {
          int row = wv * 32 + i * 16 + fr;
          a[i] = *(const bf16x8*)&As[row * 64 + (((kk * 4 + hi) ^ (row & 7)) * 8)];
        }
#pragma unroll
        for (int j = 0; j < 2; ++j) {
          int row = j * 16 + fr;
          bb[j] = *(const bf16x8*)&Bs[row * 64 + (((kk * 4 + hi) ^ (row & 7)) * 8)];
        }
#pragma unroll
        for (int i = 0; i < 2; ++i)
#pragma unroll
          for (int j = 0; j < 2; ++j)
            acc[i][j] = __builtin_amdgcn_mfma_f32_16x16x32_bf16(a[i], bb[j], acc[i][j], 0, 0, 0);
      }
      __syncthreads();
    }
  }

  float* pb = part + ((size_t)(b * 3 + ks)) * PXP * 32;
#pragma unroll
  for (int i = 0; i < 2; ++i)
#pragma unroll
    for (int j = 0; j < 2; ++j) {
      int row0 = pxp0 + wv * 32 + i * 16 + hi * 4;
      int col = j * 16 + fr;
#pragma unroll
      for (int q = 0; q < 4; ++q)
        pb[(size_t)(row0 + q) * 32 + col] = acc[i][j][q];
    }
}

// ---------------- bilinear tables (padded ids; sums 3 partials + bias) -----
__global__ void k_table(const float* __restrict__ part, const float* __restrict__ ob,
                        int4* __restrict__ tabi, float4* __restrict__ tabw) {
  int b = blockIdx.z, k = blockIdx.y;
  int px = blockIdx.x * 256 + threadIdx.x;
  int h = px / WIDTH, w = px - h * WIDTH;
  size_t pxp = (size_t)(h + 1) * 128 + (w + 1);
  const float* pb = part + (size_t)b * 3 * PXP * 32 + pxp * 32;
  float dy = ob[2 * k] + pb[2 * k] + pb[(size_t)PXP * 32 + 2 * k] + pb[2 * (size_t)PXP * 32 + 2 * k];
  float dx = ob[2 * k + 1] + pb[2 * k + 1] + pb[(size_t)PXP * 32 + 2 * k + 1] + pb[2 * (size_t)PXP * 32 + 2 * k + 1];
  float py = (float)(h - 1 + k / 3) + dy;
  float pxx = (float)(w - 1 + k % 3) + dx;
  float y0 = floorf(py), x0 = floorf(pxx);
  float ay = py - y0, ax = pxx - x0;
  float wy[2] = {1.f - ay, ay}, wx[2] = {1.f - ax, ax};
  int idx[4]; float wt[4];
#pragma unroll
  for (int t = 0; t < 4; ++t) {
    float oy = y0 + (float)(t >> 1);
    float ox = x0 + (float)(t & 1);
    bool valid = (oy >= 0.f) && (oy <= 95.f) && (ox >= 0.f) && (ox <= 95.f);
    int yi = (int)fminf(fmaxf(oy, 0.f), 95.f);
    int xi = (int)fminf(fmaxf(ox, 0.f), 95.f);
    idx[t] = (yi + 1) * 128 + (xi + 1);
    wt[t] = valid ? wy[t >> 1] * wx[t & 1] : 0.f;
  }
  size_t e = (size_t)b * TABSTRIDE + (size_t)k * HW + px;
  tabi[e] = make_int4(idx[0], idx[1], idx[2], idx[3]);
  tabw[e] = make_float4(wt[0], wt[1], wt[2], wt[3]);
}

// ---------------- sampled from ftp: samp[px][kloc*C+c], row stride rowK ----
// grid (144, C/64, 2*nk); z: b = z&1, kloc = z>>1; k = kbase + kloc
__global__ void __launch_bounds__(256) k_sample_t(
    const unsigned short* __restrict__ ftp,
    const int4* __restrict__ tabi, const float4* __restrict__ tabw,
    unsigned short* __restrict__ samp, int C, int kbase, int rowK) {
  const int z = blockIdx.z;
  const int b = z & 1, kloc = z >> 1;
  const int k = kbase + kloc;
  const int t = threadIdx.x;
  const int px = blockIdx.x * 64 + (t >> 2);
  const int c = blockIdx.y * 64 + (t & 3) * 16;
  const unsigned short* fb = ftp + (size_t)b * FTPROWS * C + 128 * C;
  size_t e = (size_t)b * TABSTRIDE + (size_t)k * HW + px;
  int4 id = tabi[e];
  float4 wt = tabw[e];
  float acc[16];
#pragma unroll
  for (int j = 0; j < 16; ++j) acc[j] = 0.f;
  const int ids[4] = {id.x, id.y, id.z, id.w};
  const float wts[4] = {wt.x, wt.y, wt.z, wt.w};
#pragma unroll
  for (int s = 0; s < 4; ++s) {
    const unsigned short* p = fb + (size_t)ids[s] * C + c;
    u16x8 v0 = *(const u16x8*)p;
    u16x8 v1 = *(const u16x8*)(p + 8);
    float wgt = wts[s];
#pragma unroll
    for (int j = 0; j < 8; ++j) acc[j] += wgt * bf2f(v0[j]);
#pragma unroll
    for (int j = 0; j < 8; ++j) acc[8 + j] += wgt * bf2f(v1[j]);
  }
  u16x8 o0, o1;
#pragma unroll
  for (int j = 0; j < 8; ++j) o0[j] = f2bf(acc[j]);
#pragma unroll
  for (int j = 0; j < 8; ++j) o1[j] = f2bf(acc[8 + j]);
  unsigned short* dst = samp + ((size_t)b * HW + px) * rowK + kloc * C + c;
  *(u16x8*)dst = o0;
  *(u16x8*)(dst + 8) = o1;
}

// ---------------- weight prep: Ap[m][k*C+c] = dw[m][c][k] (bf16) ----------
__global__ void k_prepA(const float* __restrict__ dw, unsigned short* __restrict__ Ap,
                        int C) {
  int o = blockIdx.x * 256 + threadIdx.x;
  int K = 9 * C;
  int m = o / K, r = o - m * K;
  int k = r / C, c = r - k * C;
  Ap[o] = f2bf(dw[((size_t)m * C + c) * 9 + k]);
}

// ---------------- bf16 MFMA GEMM: tile 128m x 96n, BK=64, XOR-swizzled -----
// grid (96, M/128, 2), 256 thr (4 waves as 2x2 of 64m x 48n)
__global__ void __launch_bounds__(256) k_dcgemm(
    const unsigned short* __restrict__ Ap, const unsigned short* __restrict__ Bt,
    float* __restrict__ Y, int lda, int rowK, int aOff, int accum) {
  __shared__ unsigned short As[128 * 64];  // 16 KB
  __shared__ unsigned short Bs[96 * 64];   // 12 KB
  const int tid = threadIdx.x;
  const int lane = tid & 63, wv = tid >> 6;
  const int b = blockIdx.z;
  const int m0 = blockIdx.y << 7, n0 = blockIdx.x * 96;
  const unsigned short* Ag = Ap + (size_t)m0 * lda + aOff;
  const unsigned short* Bg = Bt + ((size_t)b * HW + n0) * rowK;

  const int lr = lane >> 3;       // row-in-unit (8 rows of 128B per 1KB unit)
  const int lu = lane & 7;        // 16B-unit-in-row
  const int wm = (wv >> 1) * 64, wn = (wv & 1) * 48;
  const int fr = lane & 15, hi = lane >> 4;

  f32x4 acc[4][3];
#pragma unroll
  for (int i = 0; i < 4; ++i)
#pragma unroll
    for (int j = 0; j < 3; ++j) acc[i][j] = (f32x4){0.f, 0.f, 0.f, 0.f};

  for (int kt = 0; kt < rowK; kt += 64) {
    // stage A: wave wv -> units 4wv..4wv+3 (rows wv*32..+31)
#pragma unroll
    for (int q = 0; q < 4; ++q) {
      int row = wv * 32 + q * 8 + lr;
      int su = lu ^ (row & 7);
      GLDS(Ag + (size_t)row * lda + kt + su * 8, (char*)As + (wv * 4 + q) * 1024);
    }
    // stage B: wave wv -> units 3wv..3wv+2 (rows wv*24..+23)
#pragma unroll
    for (int q = 0; q < 3; ++q) {
      int row = wv * 24 + q * 8 + lr;
      int su = lu ^ (row & 7);
      GLDS(Bg + (size_t)row * rowK + kt + su * 8, (char*)Bs + (wv * 3 + q) * 1024);
    }
    asm volatile("s_waitcnt vmcnt(0)" ::: "memory");
    __syncthreads();
#pragma unroll
    for (int kk = 0; kk < 2; ++kk) {
      bf16x8 a[4], bb[3];
#pragma unroll
      for (int i = 0; i < 4; ++i) {
        int row = wm + i * 16 + fr;
        a[i] = *(const bf16x8*)&As[row * 64 + (((kk * 4 + hi) ^ (row & 7)) * 8)];
      }
#pragma unroll
      for (int j = 0; j < 3; ++j) {
        int row = wn + j * 16 + fr;
        bb[j] = *(const bf16x8*)&Bs[row * 64 + (((kk * 4 + hi) ^ (row & 7)) * 8)];
      }
#pragma unroll
      for (int i = 0; i < 4; ++i)
#pragma unroll
        for (int j = 0; j < 3; ++j)
          acc[i][j] = __builtin_amdgcn_mfma_f32_16x16x32_bf16(a[i], bb[j], acc[i][j], 0, 0, 0);
    }
    __syncthreads();
  }

  float* Yb = Y + (size_t)b * FSTRIDE;
  const int orow = m0 + wm + hi * 4;
  const int ocol = n0 + wn + fr;
#pragma unroll
  for (int i = 0; i < 4; ++i) {
#pragma unroll
    for (int j = 0; j < 3; ++j) {
      float* p = Yb + (size_t)(orow + i * 16) * HW + ocol + j * 16;
#pragma unroll
      for (int q = 0; q < 4; ++q) {
        float v = acc[i][j][q];
        if (accum) v += p[(size_t)q * HW];
        p[(size_t)q * HW] = v;
      }
    }
  }
}

// ---------------- GroupNorm stats: stage 1 ----------------
__global__ void __launch_bounds__(256) k_gnstats1(const float* __restrict__ y,
                                                  float2* __restrict__ part, int CperG) {
  const int b = blockIdx.z, g = blockIdx.x, ch = blockIdx.y;
  const int n = CperG * HW;
  const int cs = n >> 4;
  const int cs4 = cs >> 2;
  const float4* p = (const float4*)(y + (size_t)b * FSTRIDE + (size_t)g * n + (size_t)ch * cs);
  float s = 0.f, q = 0.f;
  for (int i = threadIdx.x; i < cs4; i += 256) {
    float4 v = p[i];
    s += v.x + v.y + v.z + v.w;
    q += v.x * v.x + v.y * v.y + v.z * v.z + v.w * v.w;
  }
  __shared__ float ss[256], qs[256];
  ss[threadIdx.x] = s; qs[threadIdx.x] = q;
  __syncthreads();
  for (int d = 128; d > 0; d >>= 1) {
    if (threadIdx.x < d) { ss[threadIdx.x] += ss[threadIdx.x + d]; qs[threadIdx.x] += qs[threadIdx.x + d]; }
    __syncthreads();
  }
  if (threadIdx.x == 0) part[((b << 5) + g) * 16 + ch] = make_float2(ss[0], qs[0]);
}

// ---------------- GroupNorm stats: stage 2 ----------------
__global__ void k_gnfin(const float2* __restrict__ part, float2* __restrict__ stat,
                        int CperG) {
  int t = threadIdx.x;
  float s = 0.f, q = 0.f;
#pragma unroll
  for (int j = 0; j < 16; ++j) { float2 v = part[t * 16 + j]; s += v.x; q += v.y; }
  float n = (float)(CperG * HW);
  float m = s / n;
  float var = q / n - m * m;
  stat[t] = make_float2(m, rsqrtf(var + 1e-5f));
}

// ---------------- GroupNorm apply + ReLU (float4) — layer 4 only ----------
__global__ void k_gnapply(const float* __restrict__ y, const float2* __restrict__ stat,
                          const float* __restrict__ gamma, const float* __restrict__ beta,
                          float* __restrict__ out, int CperG, size_t ostride) {
  int b = blockIdx.z;
  int i = (blockIdx.x * 256 + threadIdx.x) * 4;
  int c = i / HW;
  float2 st = stat[b * 32 + c / CperG];
  float ga = gamma[c], be = beta[c];
  float4 v = *(const float4*)(y + (size_t)b * FSTRIDE + i);
  v.x = fmaxf((v.x - st.x) * st.y * ga + be, 0.f);
  v.y = fmaxf((v.y - st.x) * st.y * ga + be, 0.f);
  v.z = fmaxf((v.z - st.x) * st.y * ga + be, 0.f);
  v.w = fmaxf((v.w - st.x) * st.y * ga + be, 0.f);
  *(float4*)(out + (size_t)b * ostride + i) = v;
}

// ---------------- cosine-sim: stage 1 ----------------
__global__ void k_cos1(const float* __restrict__ res, float4* __restrict__ part) {
  int px = blockIdx.x * 256 + threadIdx.x;
  int cc = blockIdx.y;
  float saa = 0.f, sbb = 0.f, sab = 0.f;
  for (int c = cc * 32; c < cc * 32 + 32; ++c) {
    float a = res[(size_t)c * HW + px];
    float bb = res[2 * (size_t)RSTRIDE + (size_t)c * HW + px];
    saa += a * a; sbb += bb * bb; sab += a * bb;
  }
  part[(size_t)cc * HW + px] = make_float4(saa, sbb, sab, 0.f);
}

// ---------------- cosine-sim: stage 2 ----------------
__global__ void k_cos2(const float4* __restrict__ part, float* __restrict__ wpix) {
  int px = blockIdx.x * 256 + threadIdx.x;
  float saa = 0.f, sbb = 0.f, sab = 0.f;
#pragma unroll
  for (int cc = 0; cc < 8; ++cc) {
    float4 v = part[(size_t)cc * HW + px];
    saa += v.x; sbb += v.y; sab += v.z;
  }
  float na = sqrtf(saa), nb = sqrtf(sbb);
  float ttw = saa / fmaxf(na * na, 1e-8f);
  float tkw = sab / fmaxf(na * nb, 1e-8f);
  float m = fmaxf(ttw, tkw);
  float e0 = expf(ttw - m), e1 = expf(tkw - m);
  wpix[px] = e0 / (e0 + e1);
}

// ---------------- final blend ----------------
__global__ void k_combine(const float* __restrict__ res, const float* __restrict__ wpix,
                          float* __restrict__ out) {
  int i = blockIdx.x * 256 + threadIdx.x;
  int px = i % HW;
  float w0 = wpix[px];
  out[i] = w0 * res[i] + (1.f - w0) * res[2 * (size_t)RSTRIDE + i];
}

extern "C" void kernel_launch(void* const* d_in, const int* in_sizes, int n_in,
                              void* d_out, int out_size, void* d_ws, size_t ws_size,
                              hipStream_t stream) {
  const float* datas = (const float*)d_in[0];
  const float* ow[4] = {(const float*)d_in[1], (const float*)d_in[6],
                        (const float*)d_in[11], (const float*)d_in[16]};
  const float* ob[4] = {(const float*)d_in[2], (const float*)d_in[7],
                        (const float*)d_in[12], (const float*)d_in[17]};
  const float* dw[4] = {(const float*)d_in[3], (const float*)d_in[8],
                        (const float*)d_in[13], (const float*)d_in[18]};
  const float* gg[4] = {(const float*)d_in[4], (const float*)d_in[9],
                        (const float*)d_in[14], (const float*)d_in[19]};
  const float* gb[4] = {(const float*)d_in[5], (const float*)d_in[10],
                        (const float*)d_in[15], (const float*)d_in[20]};

  // full-K path needs ~268.2 MB of workspace; fall back to 3-chunk otherwise
  const int fullk = (ws_size >= 268500000ull) ? 1 : 0;
  const size_t sampN = fullk ? (2 * (size_t)HW * 4608) : (2 * (size_t)HW * 1536);

  float* ws = (float*)d_ws;
  float* y     = ws;                                      // 2*FSTRIDE fp32
  float* offp3 = y + 2 * (size_t)FSTRIDE;                 // 2*3*PXP*32 fp32
  float4* tabw = (float4*)(offp3 + 2 * 3 * (size_t)PXP * 32);
  int4*   tabi = (int4*)(tabw + 2 * (size_t)TABSTRIDE);
  float* wpix = (float*)(tabi + 2 * (size_t)TABSTRIDE);   // HW
  float2* stat = (float2*)(wpix + HW);                    // 64
  float2* gnpart = stat + 64;                             // 1024
  float4* cospart = (float4*)(gnpart + 1024);             // 8*HW
  float* endp = (float*)(cospart + 8 * (size_t)HW);
  size_t ofs = ((size_t)(endp - ws) + 3) & ~(size_t)3;
  unsigned short* samp = (unsigned short*)(ws + ofs);
  unsigned short* Ap = samp + sampN;                      // 512*4608
  unsigned short* Wt = Ap + (size_t)512 * 4608;           // 9*32*512
  unsigned short* ftp512 = Wt + (size_t)9 * 32 * 512;     // 2*FTPROWS*512
  unsigned short* ftp256 = ftp512 + 2 * (size_t)FTPROWS * 512;  // 2*FTPROWS*256

  dim3 blk(256);
  k_zero<<<dim3(2 * FTPROWS * 512 / 8 / 256), blk, 0, stream>>>(ftp512, 2u * FTPROWS * 512 / 8);
  k_zero<<<dim3(2 * FTPROWS * 256 / 8 / 256), blk, 0, stream>>>(ftp256, 2u * FTPROWS * 256 / 8);

  for (int l = 0; l < 4; ++l) {
    const int Cx = (l < 3) ? 512 : 256;
    const int M  = Cx;
    // build 512-ch ftp for the offset conv (layer l input = gn(y_{l-1}) or concat)
    if (l == 0) {
      k_mkftp_cat<<<dim3(144, 8, 2), blk, 0, stream>>>(datas + RSTRIDE, datas,
                                                       datas + RSTRIDE, ftp512, 512, 256);
    } else {
      k_gnstats1<<<dim3(32, 16, 2), blk, 0, stream>>>(y, gnpart, 16);
      k_gnfin<<<dim3(1), dim3(64), 0, stream>>>(gnpart, stat, 16);
      k_mkftp_gn<<<dim3(144, 8, 2), blk, 0, stream>>>(y, stat, gg[l - 1], gb[l - 1], ftp512);
    }
    k_prepA<<<dim3(M * 9 * Cx / 256), blk, 0, stream>>>(dw[l], Ap, Cx);
    k_prepW<<<dim3(9 * 32 * 512 / 256), blk, 0, stream>>>(ow[l], Wt);
    k_offmm<<<dim3(96, 3, 2), blk, 0, stream>>>(ftp512, Wt, offp3);
    k_table<<<dim3(36, 9, 2), blk, 0, stream>>>(offp3, ob[l], tabi, tabw);
    const unsigned short* sftp;
    if (l < 3) {
      sftp = ftp512;
    } else {
      k_mkftp_cat<<<dim3(144, 4, 2), blk, 0, stream>>>(datas + RSTRIDE, datas,
                                                       datas, ftp256, 256, 256);
      sftp = ftp256;
    }
    const int nch = fullk ? 1 : 3;
    const int nk = 9 / nch;
    const int rowK = nk * Cx;
    for (int ch = 0; ch < nch; ++ch) {
      k_sample_t<<<dim3(144, Cx / 64, 2 * nk), blk, 0, stream>>>(sftp, tabi, tabw, samp,
                                                                 Cx, ch * nk, rowK);
      k_dcgemm<<<dim3(96, M / 128, 2), blk, 0, stream>>>(Ap, samp, y, 9 * Cx, rowK,
                                                         ch * rowK, ch > 0);
    }
  }

  // layer-4 GN -> res, then cosine blend
  k_gnstats1<<<dim3(32, 16, 2), blk, 0, stream>>>(y, gnpart, 8);
  k_gnfin<<<dim3(1), dim3(64), 0, stream>>>(gnpart, stat, 8);
  float* res = y + RSTRIDE;  // b-stride 2*RSTRIDE (upper halves of y are free)
  k_gnapply<<<dim3(RSTRIDE / 1024, 1, 2), blk, 0, stream>>>(y, stat, gg[3], gb[3], res,
                                                            8, 2 * (size_t)RSTRIDE);
  k_cos1<<<dim3(36, 8), blk, 0, stream>>>(res, cospart);
  k_cos2<<<dim3(36), blk, 0, stream>>>(cospart, wpix);
  k_combine<<<dim3(RSTRIDE / 256), blk, 0, stream>>>(res, wpix, (float*)d_out);
}

// Round 6
// 1062.657 us; speedup vs baseline: 7.8638x; 1.0405x over previous
//
#include <hip/hip_runtime.h>
#include <math.h>

#define HW 9216
#define WIDTH 96
#define FSTRIDE (512*HW)          // 4718592
#define RSTRIDE (256*HW)          // 2359296
#define TABSTRIDE (9*HW)          // 82944
#define PXP 12544                 // 98 rows * 128
#define FTPROWS 12800             // 100 rows (guard + 98 + guard)

typedef __attribute__((ext_vector_type(8))) short bf16x8;
typedef __attribute__((ext_vector_type(4))) float f32x4;
typedef __attribute__((ext_vector_type(8))) unsigned short u16x8;

__device__ __forceinline__ unsigned short f2bf(float f) {
  unsigned int u = __float_as_uint(f);
  u += 0x7FFFu + ((u >> 16) & 1u);   // RNE
  return (unsigned short)(u >> 16);
}
__device__ __forceinline__ float bf2f(unsigned short s) {
  return __uint_as_float(((unsigned int)s) << 16);
}

#define GLDS(g, l) __builtin_amdgcn_global_load_lds( \
    (const __attribute__((address_space(1))) unsigned int*)(g), \
    (__attribute__((address_space(3))) unsigned int*)(l), 16, 0, 0)

// ---------------- zero helper ----------------
__global__ void k_zero(unsigned short* p, unsigned int n8) {
  unsigned int i = blockIdx.x * 256 + threadIdx.x;
  if (i < n8) ((u16x8*)p)[i] = (u16x8){0, 0, 0, 0, 0, 0, 0, 0};
}

// ---------------- ftp from concat sources: [b][pxp][C] bf16 ----------------
__global__ void __launch_bounds__(256) k_mkftp_cat(
    const float* __restrict__ lo0, const float* __restrict__ lo1,
    const float* __restrict__ hi, unsigned short* __restrict__ dst,
    int C, int CB) {
  const int b = blockIdx.z;
  const float* lo = b ? lo1 : lo0;
  unsigned short* d = dst + (size_t)b * FTPROWS * C + 128 * C;
  const int px0 = blockIdx.x * 64, c0 = blockIdx.y * 64;
  __shared__ float tile[64][65];
  const int t = threadIdx.x;
#pragma unroll
  for (int rep = 0; rep < 16; ++rep) {
    int idx = rep * 256 + t;
    int cl = idx >> 6, pl = idx & 63;
    int cg = c0 + cl;
    const float* s = (cg < CB) ? (lo + (size_t)cg * HW) : (hi + (size_t)(cg - CB) * HW);
    tile[cl][pl] = s[px0 + pl];
  }
  __syncthreads();
  const int pl = t >> 2, cu = (t & 3) * 16;
  const int px = px0 + pl;
  const int h = px / WIDTH, w = px - h * WIDTH;
  const size_t pxp = (size_t)(h + 1) * 128 + (w + 1);
  u16x8 o0, o1;
#pragma unroll
  for (int j = 0; j < 8; ++j) o0[j] = f2bf(tile[cu + j][pl]);
#pragma unroll
  for (int j = 0; j < 8; ++j) o1[j] = f2bf(tile[cu + 8 + j][pl]);
  unsigned short* p = d + pxp * C + c0 + cu;
  *(u16x8*)p = o0;
  *(u16x8*)(p + 8) = o1;
}

// ---------------- ftp from GN(y)+ReLU (C=512, CperG=16) ----------------
__global__ void __launch_bounds__(256) k_mkftp_gn(
    const float* __restrict__ y, const float2* __restrict__ stat,
    const float* __restrict__ gamma, const float* __restrict__ beta,
    unsigned short* __restrict__ dst) {
  const int C = 512;
  const int b = blockIdx.z;
  unsigned short* d = dst + (size_t)b * FTPROWS * C + 128 * C;
  const int px0 = blockIdx.x * 64, c0 = blockIdx.y * 64;
  __shared__ float tile[64][65];
  const int t = threadIdx.x;
#pragma unroll
  for (int rep = 0; rep < 16; ++rep) {
    int idx = rep * 256 + t;
    int cl = idx >> 6, pl = idx & 63;
    int cg = c0 + cl;
    float2 st = stat[b * 32 + (cg >> 4)];
    float v = y[(size_t)b * FSTRIDE + (size_t)cg * HW + px0 + pl];
    v = (v - st.x) * st.y * gamma[cg] + beta[cg];
    tile[cl][pl] = fmaxf(v, 0.f);
  }
  __syncthreads();
  const int pl = t >> 2, cu = (t & 3) * 16;
  const int px = px0 + pl;
  const int h = px / WIDTH, w = px - h * WIDTH;
  const size_t pxp = (size_t)(h + 1) * 128 + (w + 1);
  u16x8 o0, o1;
#pragma unroll
  for (int j = 0; j < 8; ++j) o0[j] = f2bf(tile[cu + j][pl]);
#pragma unroll
  for (int j = 0; j < 8; ++j) o1[j] = f2bf(tile[cu + 8 + j][pl]);
  unsigned short* p = d + pxp * C + c0 + cu;
  *(u16x8*)p = o0;
  *(u16x8*)(p + 8) = o1;
}

// ---------------- offconv weights: Wt[k][oc(32 pad)][c] bf16 ----------------
__global__ void k_prepW(const float* __restrict__ ow, unsigned short* __restrict__ Wt) {
  int i = blockIdx.x * 256 + threadIdx.x;  // < 9*32*512
  int k = i / (32 * 512), r = i - k * 32 * 512;
  int oc = r / 512, c = r - oc * 512;
  Wt[i] = (oc < 18) ? f2bf(ow[((size_t)oc * 512 + c) * 9 + k]) : (unsigned short)0;
}

// ---------------- offset conv via MFMA: part[b][ks][pxp][32] ----------------
__global__ void __launch_bounds__(256) k_offmm(const unsigned short* __restrict__ ftp,
                                               const unsigned short* __restrict__ Wt,
                                               float* __restrict__ part) {
  const int C = 512;
  __shared__ unsigned short As[128 * 64];
  __shared__ unsigned short Bs[32 * 64];
  const int tid = threadIdx.x;
  const int lane = tid & 63, wv = tid >> 6;
  const int b = blockIdx.z, ks = blockIdx.y;
  const int pxp0 = 128 + blockIdx.x * 128;
  const unsigned short* fb = ftp + (size_t)b * FTPROWS * C + 128 * C;

  const int lr = lane >> 3;
  const int lu = lane & 7;
  const int fr = lane & 15, hi = lane >> 4;

  f32x4 acc[2][2];
#pragma unroll
  for (int i = 0; i < 2; ++i)
#pragma unroll
    for (int j = 0; j < 2; ++j) acc[i][j] = (f32x4){0.f, 0.f, 0.f, 0.f};

  for (int kt = 0; kt < 3; ++kt) {
    const int k = ks * 3 + kt;
    const int dlt = (k / 3 - 1) * 128 + (k % 3 - 1);
    for (int c0 = 0; c0 < C; c0 += 64) {
#pragma unroll
      for (int q = 0; q < 4; ++q) {
        int row = wv * 32 + q * 8 + lr;
        int su = lu ^ (row & 7);
        GLDS(fb + (size_t)(pxp0 + dlt + row) * C + c0 + su * 8,
             (char*)As + (wv * 32 + q * 8) * 128);
      }
      {
        int row = wv * 8 + lr;
        int su = lu ^ (row & 7);
        GLDS(Wt + ((size_t)k * 32 + row) * C + c0 + su * 8,
             (char*)Bs + wv * 8 * 128);
      }
      asm volatile("s_waitcnt vmcnt(0)" ::: "memory");
      __syncthreads();
#pragma unroll
      for (int kk = 0; kk < 2; ++kk) {
        bf16x8 a[2], bb[2];
#pragma unroll
        for (int i = 0; i < 2; ++i) {
          int row = wv * 32 + i * 16 + fr;
          a[i] = *(const bf16x8*)&As[row * 64 + (((kk * 4 + hi) ^ (row & 7)) * 8)];
        }
#pragma unroll
        for (int j = 0; j < 2; ++j) {
          int row = j * 16 + fr;
          bb[j] = *(const bf16x8*)&Bs[row * 64 + (((kk * 4 + hi) ^ (row & 7)) * 8)];
        }
#pragma unroll
        for (int i = 0; i < 2; ++i)
#pragma unroll
          for (int j = 0; j < 2; ++j)
            acc[i][j] = __builtin_amdgcn_mfma_f32_16x16x32_bf16(a[i], bb[j], acc[i][j], 0, 0, 0);
      }
      __syncthreads();
    }
  }

  float* pb = part + ((size_t)(b * 3 + ks)) * PXP * 32;
#pragma unroll
  for (int i = 0; i < 2; ++i)
#pragma unroll
    for (int j = 0; j < 2; ++j) {
      int row0 = pxp0 + wv * 32 + i * 16 + hi * 4;
      int col = j * 16 + fr;
#pragma unroll
      for (int q = 0; q < 4; ++q)
        pb[(size_t)(row0 + q) * 32 + col] = acc[i][j][q];
    }
}

// ---------------- bilinear tables (padded ids; sums 3 partials + bias) -----
__global__ void k_table(const float* __restrict__ part, const float* __restrict__ ob,
                        int4* __restrict__ tabi, float4* __restrict__ tabw) {
  int b = blockIdx.z, k = blockIdx.y;
  int px = blockIdx.x * 256 + threadIdx.x;
  int h = px / WIDTH, w = px - h * WIDTH;
  size_t pxp = (size_t)(h + 1) * 128 + (w + 1);
  const float* pb = part + (size_t)b * 3 * PXP * 32 + pxp * 32;
  float dy = ob[2 * k] + pb[2 * k] + pb[(size_t)PXP * 32 + 2 * k] + pb[2 * (size_t)PXP * 32 + 2 * k];
  float dx = ob[2 * k + 1] + pb[2 * k + 1] + pb[(size_t)PXP * 32 + 2 * k + 1] + pb[2 * (size_t)PXP * 32 + 2 * k + 1];
  float py = (float)(h - 1 + k / 3) + dy;
  float pxx = (float)(w - 1 + k % 3) + dx;
  float y0 = floorf(py), x0 = floorf(pxx);
  float ay = py - y0, ax = pxx - x0;
  float wy[2] = {1.f - ay, ay}, wx[2] = {1.f - ax, ax};
  int idx[4]; float wt[4];
#pragma unroll
  for (int t = 0; t < 4; ++t) {
    float oy = y0 + (float)(t >> 1);
    float ox = x0 + (float)(t & 1);
    bool valid = (oy >= 0.f) && (oy <= 95.f) && (ox >= 0.f) && (ox <= 95.f);
    int yi = (int)fminf(fmaxf(oy, 0.f), 95.f);
    int xi = (int)fminf(fmaxf(ox, 0.f), 95.f);
    idx[t] = (yi + 1) * 128 + (xi + 1);
    wt[t] = valid ? wy[t >> 1] * wx[t & 1] : 0.f;
  }
  size_t e = (size_t)b * TABSTRIDE + (size_t)k * HW + px;
  tabi[e] = make_int4(idx[0], idx[1], idx[2], idx[3]);
  tabw[e] = make_float4(wt[0], wt[1], wt[2], wt[3]);
}

// ---------------- sampled from ftp: samp[px][kloc*C+c], row stride rowK ----
// grid (144, C/64, 2*nk); z: b = z&1, kloc = z>>1; k = kbase + kloc
__global__ void __launch_bounds__(256) k_sample_t(
    const unsigned short* __restrict__ ftp,
    const int4* __restrict__ tabi, const float4* __restrict__ tabw,
    unsigned short* __restrict__ samp, int C, int kbase, int rowK) {
  const int z = blockIdx.z;
  const int b = z & 1, kloc = z >> 1;
  const int k = kbase + kloc;
  const int t = threadIdx.x;
  const int px = blockIdx.x * 64 + (t >> 2);
  const int c = blockIdx.y * 64 + (t & 3) * 16;
  const unsigned short* fb = ftp + (size_t)b * FTPROWS * C + 128 * C;
  size_t e = (size_t)b * TABSTRIDE + (size_t)k * HW + px;
  int4 id = tabi[e];
  float4 wt = tabw[e];
  float acc[16];
#pragma unroll
  for (int j = 0; j < 16; ++j) acc[j] = 0.f;
  const int ids[4] = {id.x, id.y, id.z, id.w};
  const float wts[4] = {wt.x, wt.y, wt.z, wt.w};
#pragma unroll
  for (int s = 0; s < 4; ++s) {
    const unsigned short* p = fb + (size_t)ids[s] * C + c;
    u16x8 v0 = *(const u16x8*)p;
    u16x8 v1 = *(const u16x8*)(p + 8);
    float wgt = wts[s];
#pragma unroll
    for (int j = 0; j < 8; ++j) acc[j] += wgt * bf2f(v0[j]);
#pragma unroll
    for (int j = 0; j < 8; ++j) acc[8 + j] += wgt * bf2f(v1[j]);
  }
  u16x8 o0, o1;
#pragma unroll
  for (int j = 0; j < 8; ++j) o0[j] = f2bf(acc[j]);
#pragma unroll
  for (int j = 0; j < 8; ++j) o1[j] = f2bf(acc[8 + j]);
  unsigned short* dst = samp + ((size_t)b * HW + px) * rowK + kloc * C + c;
  *(u16x8*)dst = o0;
  *(u16x8*)(dst + 8) = o1;
}

// ---------------- weight prep: Ap[m][k*C+c] = dw[m][c][k] (bf16) ----------
__global__ void k_prepA(const float* __restrict__ dw, unsigned short* __restrict__ Ap,
                        int C) {
  int o = blockIdx.x * 256 + threadIdx.x;
  int K = 9 * C;
  int m = o / K, r = o - m * K;
  int k = r / C, c = r - k * C;
  Ap[o] = f2bf(dw[((size_t)m * C + c) * 9 + k]);
}

// ---------------- staging helper: 4 A-units + 3 B-units per wave ----------
__device__ __forceinline__ void stage_ab(const unsigned short* __restrict__ Ag,
                                         const unsigned short* __restrict__ Bg,
                                         int lda, int rowK, int kt,
                                         unsigned short* as_, unsigned short* bs_,
                                         int wv, int lr, int lu) {
#pragma unroll
  for (int q = 0; q < 4; ++q) {
    int row = wv * 32 + q * 8 + lr;
    int su = lu ^ (row & 7);
    GLDS(Ag + (size_t)row * lda + kt + su * 8, (char*)as_ + (wv * 4 + q) * 1024);
  }
#pragma unroll
  for (int q = 0; q < 3; ++q) {
    int row = wv * 24 + q * 8 + lr;
    int su = lu ^ (row & 7);
    GLDS(Bg + (size_t)row * rowK + kt + su * 8, (char*)bs_ + (wv * 3 + q) * 1024);
  }
}

// ---------------- bf16 MFMA GEMM: 128m x 96n, BK=64, dbuf + counted vmcnt --
// grid (96, M/128, 2), 256 thr (2x2 waves of 64m x 48n). 7 GLDS/wave/step.
__global__ void __launch_bounds__(256) k_dcgemm(
    const unsigned short* __restrict__ Ap, const unsigned short* __restrict__ Bt,
    float* __restrict__ Y, int lda, int rowK, int aOff, int accum) {
  __shared__ unsigned short As[2][128 * 64];  // 2 x 16 KB
  __shared__ unsigned short Bs[2][96 * 64];   // 2 x 12 KB
  const int tid = threadIdx.x;
  const int lane = tid & 63, wv = tid >> 6;
  const int b = blockIdx.z;
  const int m0 = blockIdx.y << 7, n0 = blockIdx.x * 96;
  const unsigned short* Ag = Ap + (size_t)m0 * lda + aOff;
  const unsigned short* Bg = Bt + ((size_t)b * HW + n0) * rowK;

  const int lr = lane >> 3, lu = lane & 7;
  const int wm = (wv >> 1) * 64, wn = (wv & 1) * 48;
  const int fr = lane & 15, hi = lane >> 4;
  const int nt = rowK >> 6;

  f32x4 acc[4][3];
#pragma unroll
  for (int i = 0; i < 4; ++i)
#pragma unroll
    for (int j = 0; j < 3; ++j) acc[i][j] = (f32x4){0.f, 0.f, 0.f, 0.f};

  stage_ab(Ag, Bg, lda, rowK, 0, &As[0][0], &Bs[0][0], wv, lr, lu);

  for (int t = 0; t < nt; ++t) {
    const int cur = t & 1;
    if (t + 1 < nt) {
      stage_ab(Ag, Bg, lda, rowK, (t + 1) << 6, &As[cur ^ 1][0], &Bs[cur ^ 1][0],
               wv, lr, lu);
      asm volatile("s_waitcnt vmcnt(7)" ::: "memory");  // drain step t, keep t+1 in flight
    } else {
      asm volatile("s_waitcnt vmcnt(0)" ::: "memory");
    }
    __builtin_amdgcn_s_barrier();
#pragma unroll
    for (int kk = 0; kk < 2; ++kk) {
      bf16x8 a[4], bb[3];
#pragma unroll
      for (int i = 0; i < 4; ++i) {
        int row = wm + i * 16 + fr;
        a[i] = *(const bf16x8*)&As[cur][row * 64 + (((kk * 4 + hi) ^ (row & 7)) * 8)];
      }
#pragma unroll
      for (int j = 0; j < 3; ++j) {
        int row = wn + j * 16 + fr;
        bb[j] = *(const bf16x8*)&Bs[cur][row * 64 + (((kk * 4 + hi) ^ (row & 7)) * 8)];
      }
#pragma unroll
      for (int i = 0; i < 4; ++i)
#pragma unroll
        for (int j = 0; j < 3; ++j)
          acc[i][j] = __builtin_amdgcn_mfma_f32_16x16x32_bf16(a[i], bb[j], acc[i][j], 0, 0, 0);
    }
    __builtin_amdgcn_s_barrier();  // all frag reads of buf[cur] done before overwrite
  }

  float* Yb = Y + (size_t)b * FSTRIDE;
  const int orow = m0 + wm + hi * 4;
  const int ocol = n0 + wn + fr;
#pragma unroll
  for (int i = 0; i < 4; ++i) {
#pragma unroll
    for (int j = 0; j < 3; ++j) {
      float* p = Yb + (size_t)(orow + i * 16) * HW + ocol + j * 16;
#pragma unroll
      for (int q = 0; q < 4; ++q) {
        float v = acc[i][j][q];
        if (accum) v += p[(size_t)q * HW];
        p[(size_t)q * HW] = v;
      }
    }
  }
}

// ---------------- GroupNorm stats: stage 1 ----------------
__global__ void __launch_bounds__(256) k_gnstats1(const float* __restrict__ y,
                                                  float2* __restrict__ part, int CperG) {
  const int b = blockIdx.z, g = blockIdx.x, ch = blockIdx.y;
  const int n = CperG * HW;
  const int cs = n >> 4;
  const int cs4 = cs >> 2;
  const float4* p = (const float4*)(y + (size_t)b * FSTRIDE + (size_t)g * n + (size_t)ch * cs);
  float s = 0.f, q = 0.f;
  for (int i = threadIdx.x; i < cs4; i += 256) {
    float4 v = p[i];
    s += v.x + v.y + v.z + v.w;
    q += v.x * v.x + v.y * v.y + v.z * v.z + v.w * v.w;
  }
  __shared__ float ss[256], qs[256];
  ss[threadIdx.x] = s; qs[threadIdx.x] = q;
  __syncthreads();
  for (int d = 128; d > 0; d >>= 1) {
    if (threadIdx.x < d) { ss[threadIdx.x] += ss[threadIdx.x + d]; qs[threadIdx.x] += qs[threadIdx.x + d]; }
    __syncthreads();
  }
  if (threadIdx.x == 0) part[((b << 5) + g) * 16 + ch] = make_float2(ss[0], qs[0]);
}

// ---------------- GroupNorm stats: stage 2 ----------------
__global__ void k_gnfin(const float2* __restrict__ part, float2* __restrict__ stat,
                        int CperG) {
  int t = threadIdx.x;
  float s = 0.f, q = 0.f;
#pragma unroll
  for (int j = 0; j < 16; ++j) { float2 v = part[t * 16 + j]; s += v.x; q += v.y; }
  float n = (float)(CperG * HW);
  float m = s / n;
  float var = q / n - m * m;
  stat[t] = make_float2(m, rsqrtf(var + 1e-5f));
}

// ---------------- GroupNorm apply + ReLU (float4) — layer 4 only ----------
__global__ void k_gnapply(const float* __restrict__ y, const float2* __restrict__ stat,
                          const float* __restrict__ gamma, const float* __restrict__ beta,
                          float* __restrict__ out, int CperG, size_t ostride) {
  int b = blockIdx.z;
  int i = (blockIdx.x * 256 + threadIdx.x) * 4;
  int c = i / HW;
  float2 st = stat[b * 32 + c / CperG];
  float ga = gamma[c], be = beta[c];
  float4 v = *(const float4*)(y + (size_t)b * FSTRIDE + i);
  v.x = fmaxf((v.x - st.x) * st.y * ga + be, 0.f);
  v.y = fmaxf((v.y - st.x) * st.y * ga + be, 0.f);
  v.z = fmaxf((v.z - st.x) * st.y * ga + be, 0.f);
  v.w = fmaxf((v.w - st.x) * st.y * ga + be, 0.f);
  *(float4*)(out + (size_t)b * ostride + i) = v;
}

// ---------------- cosine-sim: stage 1 ----------------
__global__ void k_cos1(const float* __restrict__ res, float4* __restrict__ part) {
  int px = blockIdx.x * 256 + threadIdx.x;
  int cc = blockIdx.y;
  float saa = 0.f, sbb = 0.f, sab = 0.f;
  for (int c = cc * 32; c < cc * 32 + 32; ++c) {
    float a = res[(size_t)c * HW + px];
    float bb = res[2 * (size_t)RSTRIDE + (size_t)c * HW + px];
    saa += a * a; sbb += bb * bb; sab += a * bb;
  }
  part[(size_t)cc * HW + px] = make_float4(saa, sbb, sab, 0.f);
}

// ---------------- cosine-sim: stage 2 ----------------
__global__ void k_cos2(const float4* __restrict__ part, float* __restrict__ wpix) {
  int px = blockIdx.x * 256 + threadIdx.x;
  float saa = 0.f, sbb = 0.f, sab = 0.f;
#pragma unroll
  for (int cc = 0; cc < 8; ++cc) {
    float4 v = part[(size_t)cc * HW + px];
    saa += v.x; sbb += v.y; sab += v.z;
  }
  float na = sqrtf(saa), nb = sqrtf(sbb);
  float ttw = saa / fmaxf(na * na, 1e-8f);
  float tkw = sab / fmaxf(na * nb, 1e-8f);
  float m = fmaxf(ttw, tkw);
  float e0 = expf(ttw - m), e1 = expf(tkw - m);
  wpix[px] = e0 / (e0 + e1);
}

// ---------------- final blend ----------------
__global__ void k_combine(const float* __restrict__ res, const float* __restrict__ wpix,
                          float* __restrict__ out) {
  int i = blockIdx.x * 256 + threadIdx.x;
  int px = i % HW;
  float w0 = wpix[px];
  out[i] = w0 * res[i] + (1.f - w0) * res[2 * (size_t)RSTRIDE + i];
}

extern "C" void kernel_launch(void* const* d_in, const int* in_sizes, int n_in,
                              void* d_out, int out_size, void* d_ws, size_t ws_size,
                              hipStream_t stream) {
  const float* datas = (const float*)d_in[0];
  const float* ow[4] = {(const float*)d_in[1], (const float*)d_in[6],
                        (const float*)d_in[11], (const float*)d_in[16]};
  const float* ob[4] = {(const float*)d_in[2], (const float*)d_in[7],
                        (const float*)d_in[12], (const float*)d_in[17]};
  const float* dw[4] = {(const float*)d_in[3], (const float*)d_in[8],
                        (const float*)d_in[13], (const float*)d_in[18]};
  const float* gg[4] = {(const float*)d_in[4], (const float*)d_in[9],
                        (const float*)d_in[14], (const float*)d_in[19]};
  const float* gb[4] = {(const float*)d_in[5], (const float*)d_in[10],
                        (const float*)d_in[15], (const float*)d_in[20]};

  // full-K needs: 53.92 (f32 block) + 169.87 (samp) + 4.72 (Ap) + 0.29 (Wt)
  // + 26.21 (ftp512) MB; ftp256 aliased into samp tail => total 255.02 MB.
  const int fullk = (ws_size >= 255100000ull) ? 1 : 0;
  const size_t sampN = fullk ? (2 * (size_t)HW * 4608) : (2 * (size_t)HW * 1536);

  float* ws = (float*)d_ws;
  float* y     = ws;                                      // 2*FSTRIDE fp32
  float* offp3 = y + 2 * (size_t)FSTRIDE;                 // 2*3*PXP*32 fp32
  float4* tabw = (float4*)(offp3 + 2 * 3 * (size_t)PXP * 32);
  int4*   tabi = (int4*)(tabw + 2 * (size_t)TABSTRIDE);
  float* wpix = (float*)(tabi + 2 * (size_t)TABSTRIDE);   // HW
  float2* stat = (float2*)(wpix + HW);                    // 64
  float2* gnpart = stat + 64;                             // 1024
  float4* cospart = (float4*)(gnpart + 1024);             // 8*HW
  float* endp = (float*)(cospart + 8 * (size_t)HW);
  size_t ofs = ((size_t)(endp - ws) + 3) & ~(size_t)3;
  unsigned short* samp = (unsigned short*)(ws + ofs);
  unsigned short* Ap = samp + sampN;                      // 512*4608
  unsigned short* Wt = Ap + (size_t)512 * 4608;           // 9*32*512
  unsigned short* ftp512 = Wt + (size_t)9 * 32 * 512;     // 2*FTPROWS*512
  // layer-4 256-ch ftp: aliased into samp's tail when fullk (layer-4 samp
  // uses only 2*HW*2304 of the 2*HW*4608 region); separate slot otherwise.
  unsigned short* ftp256 = fullk ? (samp + 2 * (size_t)HW * 2304)
                                 : (ftp512 + 2 * (size_t)FTPROWS * 512);

  dim3 blk(256);
  k_zero<<<dim3(2 * FTPROWS * 512 / 8 / 256), blk, 0, stream>>>(ftp512, 2u * FTPROWS * 512 / 8);

  for (int l = 0; l < 4; ++l) {
    const int Cx = (l < 3) ? 512 : 256;
    const int M  = Cx;
    // build 512-ch ftp for the offset conv (layer l input = gn(y_{l-1}) or concat)
    if (l == 0) {
      k_mkftp_cat<<<dim3(144, 8, 2), blk, 0, stream>>>(datas + RSTRIDE, datas,
                                                       datas + RSTRIDE, ftp512, 512, 256);
    } else {
      k_gnstats1<<<dim3(32, 16, 2), blk, 0, stream>>>(y, gnpart, 16);
      k_gnfin<<<dim3(1), dim3(64), 0, stream>>>(gnpart, stat, 16);
      k_mkftp_gn<<<dim3(144, 8, 2), blk, 0, stream>>>(y, stat, gg[l - 1], gb[l - 1], ftp512);
    }
    k_prepA<<<dim3(M * 9 * Cx / 256), blk, 0, stream>>>(dw[l], Ap, Cx);
    k_prepW<<<dim3(9 * 32 * 512 / 256), blk, 0, stream>>>(ow[l], Wt);
    k_offmm<<<dim3(96, 3, 2), blk, 0, stream>>>(ftp512, Wt, offp3);
    k_table<<<dim3(36, 9, 2), blk, 0, stream>>>(offp3, ob[l], tabi, tabw);
    const unsigned short* sftp;
    if (l < 3) {
      sftp = ftp512;
    } else {
      k_zero<<<dim3(2 * FTPROWS * 256 / 8 / 256), blk, 0, stream>>>(ftp256, 2u * FTPROWS * 256 / 8);
      k_mkftp_cat<<<dim3(144, 4, 2), blk, 0, stream>>>(datas + RSTRIDE, datas,
                                                       datas, ftp256, 256, 256);
      sftp = ftp256;
    }
    const int nch = fullk ? 1 : 3;
    const int nk = 9 / nch;
    const int rowK = nk * Cx;
    for (int ch = 0; ch < nch; ++ch) {
      k_sample_t<<<dim3(144, Cx / 64, 2 * nk), blk, 0, stream>>>(sftp, tabi, tabw, samp,
                                                                 Cx, ch * nk, rowK);
      k_dcgemm<<<dim3(96, M / 128, 2), blk, 0, stream>>>(Ap, samp, y, 9 * Cx, rowK,
                                                         ch * rowK, ch > 0);
    }
  }

  // layer-4 GN -> res, then cosine blend
  k_gnstats1<<<dim3(32, 16, 2), blk, 0, stream>>>(y, gnpart, 8);
  k_gnfin<<<dim3(1), dim3(64), 0, stream>>>(gnpart, stat, 8);
  float* res = y + RSTRIDE;  // b-stride 2*RSTRIDE (upper halves of y are free)
  k_gnapply<<<dim3(RSTRIDE / 1024, 1, 2), blk, 0, stream>>>(y, stat, gg[3], gb[3], res,
                                                            8, 2 * (size_t)RSTRIDE);
  k_cos1<<<dim3(36, 8), blk, 0, stream>>>(res, cospart);
  k_cos2<<<dim3(36), blk, 0, stream>>>(cospart, wpix);
  k_combine<<<dim3(RSTRIDE / 256), blk, 0, stream>>>(res, wpix, (float*)d_out);
}

// Round 7
// 995.481 us; speedup vs baseline: 8.3945x; 1.0675x over previous
//
#include <hip/hip_runtime.h>
#include <math.h>

#define HW 9216
#define WIDTH 96
#define FSTRIDE (512*HW)          // 4718592
#define RSTRIDE (256*HW)          // 2359296
#define TABSTRIDE (9*HW)          // 82944
#define PXP 12544                 // 98 rows * 128
#define FTPROWS 12800             // 100 rows (guard + 98 + guard)

typedef __attribute__((ext_vector_type(8))) short bf16x8;
typedef __attribute__((ext_vector_type(4))) float f32x4;
typedef __attribute__((ext_vector_type(8))) unsigned short u16x8;

__device__ __forceinline__ unsigned short f2bf(float f) {
  unsigned int u = __float_as_uint(f);
  u += 0x7FFFu + ((u >> 16) & 1u);   // RNE
  return (unsigned short)(u >> 16);
}
__device__ __forceinline__ float bf2f(unsigned short s) {
  return __uint_as_float(((unsigned int)s) << 16);
}

#define GLDS(g, l) __builtin_amdgcn_global_load_lds( \
    (const __attribute__((address_space(1))) unsigned int*)(g), \
    (__attribute__((address_space(3))) unsigned int*)(l), 16, 0, 0)

// ---------------- zero helper ----------------
__global__ void k_zero(unsigned short* p, unsigned int n8) {
  unsigned int i = blockIdx.x * 256 + threadIdx.x;
  if (i < n8) ((u16x8*)p)[i] = (u16x8){0, 0, 0, 0, 0, 0, 0, 0};
}

// ---------------- ftp from concat sources: [b][pxp][C] bf16 ----------------
__global__ void __launch_bounds__(256) k_mkftp_cat(
    const float* __restrict__ lo0, const float* __restrict__ lo1,
    const float* __restrict__ hi, unsigned short* __restrict__ dst,
    int C, int CB) {
  const int b = blockIdx.z;
  const float* lo = b ? lo1 : lo0;
  unsigned short* d = dst + (size_t)b * FTPROWS * C + 128 * C;
  const int px0 = blockIdx.x * 64, c0 = blockIdx.y * 64;
  __shared__ float tile[64][65];
  const int t = threadIdx.x;
#pragma unroll
  for (int rep = 0; rep < 16; ++rep) {
    int idx = rep * 256 + t;
    int cl = idx >> 6, pl = idx & 63;
    int cg = c0 + cl;
    const float* s = (cg < CB) ? (lo + (size_t)cg * HW) : (hi + (size_t)(cg - CB) * HW);
    tile[cl][pl] = s[px0 + pl];
  }
  __syncthreads();
  const int pl = t >> 2, cu = (t & 3) * 16;
  const int px = px0 + pl;
  const int h = px / WIDTH, w = px - h * WIDTH;
  const size_t pxp = (size_t)(h + 1) * 128 + (w + 1);
  u16x8 o0, o1;
#pragma unroll
  for (int j = 0; j < 8; ++j) o0[j] = f2bf(tile[cu + j][pl]);
#pragma unroll
  for (int j = 0; j < 8; ++j) o1[j] = f2bf(tile[cu + 8 + j][pl]);
  unsigned short* p = d + pxp * C + c0 + cu;
  *(u16x8*)p = o0;
  *(u16x8*)(p + 8) = o1;
}

// ---------------- ftp from GN(y)+ReLU (C=512, CperG=16) ----------------
__global__ void __launch_bounds__(256) k_mkftp_gn(
    const float* __restrict__ y, const float2* __restrict__ stat,
    const float* __restrict__ gamma, const float* __restrict__ beta,
    unsigned short* __restrict__ dst) {
  const int C = 512;
  const int b = blockIdx.z;
  unsigned short* d = dst + (size_t)b * FTPROWS * C + 128 * C;
  const int px0 = blockIdx.x * 64, c0 = blockIdx.y * 64;
  __shared__ float tile[64][65];
  const int t = threadIdx.x;
#pragma unroll
  for (int rep = 0; rep < 16; ++rep) {
    int idx = rep * 256 + t;
    int cl = idx >> 6, pl = idx & 63;
    int cg = c0 + cl;
    float2 st = stat[b * 32 + (cg >> 4)];
    float v = y[(size_t)b * FSTRIDE + (size_t)cg * HW + px0 + pl];
    v = (v - st.x) * st.y * gamma[cg] + beta[cg];
    tile[cl][pl] = fmaxf(v, 0.f);
  }
  __syncthreads();
  const int pl = t >> 2, cu = (t & 3) * 16;
  const int px = px0 + pl;
  const int h = px / WIDTH, w = px - h * WIDTH;
  const size_t pxp = (size_t)(h + 1) * 128 + (w + 1);
  u16x8 o0, o1;
#pragma unroll
  for (int j = 0; j < 8; ++j) o0[j] = f2bf(tile[cu + j][pl]);
#pragma unroll
  for (int j = 0; j < 8; ++j) o1[j] = f2bf(tile[cu + 8 + j][pl]);
  unsigned short* p = d + pxp * C + c0 + cu;
  *(u16x8*)p = o0;
  *(u16x8*)(p + 8) = o1;
}

// ---------------- offconv weights: Wt[k][oc(32 pad)][c] bf16 ----------------
__global__ void k_prepW(const float* __restrict__ ow, unsigned short* __restrict__ Wt) {
  int i = blockIdx.x * 256 + threadIdx.x;  // < 9*32*512
  int k = i / (32 * 512), r = i - k * 32 * 512;
  int oc = r / 512, c = r - oc * 512;
  Wt[i] = (oc < 18) ? f2bf(ow[((size_t)oc * 512 + c) * 9 + k]) : (unsigned short)0;
}

// ---------------- offset conv via MFMA: part[b][ks][pxp][32] ----------------
__global__ void __launch_bounds__(256) k_offmm(const unsigned short* __restrict__ ftp,
                                               const unsigned short* __restrict__ Wt,
                                               float* __restrict__ part) {
  const int C = 512;
  __shared__ unsigned short As[128 * 64];
  __shared__ unsigned short Bs[32 * 64];
  const int tid = threadIdx.x;
  const int lane = tid & 63, wv = tid >> 6;
  const int b = blockIdx.z, ks = blockIdx.y;
  const int pxp0 = 128 + blockIdx.x * 128;
  const unsigned short* fb = ftp + (size_t)b * FTPROWS * C + 128 * C;

  const int lr = lane >> 3;
  const int lu = lane & 7;
  const int fr = lane & 15, hi = lane >> 4;

  f32x4 acc[2][2];
#pragma unroll
  for (int i = 0; i < 2; ++i)
#pragma unroll
    for (int j = 0; j < 2; ++j) acc[i][j] = (f32x4){0.f, 0.f, 0.f, 0.f};

  for (int kt = 0; kt < 3; ++kt) {
    const int k = ks * 3 + kt;
    const int dlt = (k / 3 - 1) * 128 + (k % 3 - 1);
    for (int c0 = 0; c0 < C; c0 += 64) {
#pragma unroll
      for (int q = 0; q < 4; ++q) {
        int row = wv * 32 + q * 8 + lr;
        int su = lu ^ (row & 7);
        GLDS(fb + (size_t)(pxp0 + dlt + row) * C + c0 + su * 8,
             (char*)As + (wv * 32 + q * 8) * 128);
      }
      {
        int row = wv * 8 + lr;
        int su = lu ^ (row & 7);
        GLDS(Wt + ((size_t)k * 32 + row) * C + c0 + su * 8,
             (char*)Bs + wv * 8 * 128);
      }
      asm volatile("s_waitcnt vmcnt(0)" ::: "memory");
      __syncthreads();
#pragma unroll
      for (int kk = 0; kk < 2; ++kk) {
        bf16x8 a[2], bb[2];
#pragma unroll
        for (int i = 0; i < 2; ++i) {
          int row = wv * 32 + i * 16 + fr;
          a[i] = *(const bf16x8*)&As[row * 64 + (((kk * 4 + hi) ^ (row & 7)) * 8)];
        }
#pragma unroll
        for (int j = 0; j < 2; ++j) {
          int row = j * 16 + fr;
          bb[j] = *(const bf16x8*)&Bs[row * 64 + (((kk * 4 + hi) ^ (row & 7)) * 8)];
        }
#pragma unroll
        for (int i = 0; i < 2; ++i)
#pragma unroll
          for (int j = 0; j < 2; ++j)
            acc[i][j] = __builtin_amdgcn_mfma_f32_16x16x32_bf16(a[i], bb[j], acc[i][j], 0, 0, 0);
      }
      __syncthreads();
    }
  }

  float* pb = part + ((size_t)(b * 3 + ks)) * PXP * 32;
#pragma unroll
  for (int i = 0; i < 2; ++i)
#pragma unroll
    for (int j = 0; j < 2; ++j) {
      int row0 = pxp0 + wv * 32 + i * 16 + hi * 4;
      int col = j * 16 + fr;
#pragma unroll
      for (int q = 0; q < 4; ++q)
        pb[(size_t)(row0 + q) * 32 + col] = acc[i][j][q];
    }
}

// ---------------- bilinear tables (padded ids; sums 3 partials + bias) -----
__global__ void k_table(const float* __restrict__ part, const float* __restrict__ ob,
                        int4* __restrict__ tabi, float4* __restrict__ tabw) {
  int b = blockIdx.z, k = blockIdx.y;
  int px = blockIdx.x * 256 + threadIdx.x;
  int h = px / WIDTH, w = px - h * WIDTH;
  size_t pxp = (size_t)(h + 1) * 128 + (w + 1);
  const float* pb = part + (size_t)b * 3 * PXP * 32 + pxp * 32;
  float dy = ob[2 * k] + pb[2 * k] + pb[(size_t)PXP * 32 + 2 * k] + pb[2 * (size_t)PXP * 32 + 2 * k];
  float dx = ob[2 * k + 1] + pb[2 * k + 1] + pb[(size_t)PXP * 32 + 2 * k + 1] + pb[2 * (size_t)PXP * 32 + 2 * k + 1];
  float py = (float)(h - 1 + k / 3) + dy;
  float pxx = (float)(w - 1 + k % 3) + dx;
  float y0 = floorf(py), x0 = floorf(pxx);
  float ay = py - y0, ax = pxx - x0;
  float wy[2] = {1.f - ay, ay}, wx[2] = {1.f - ax, ax};
  int idx[4]; float wt[4];
#pragma unroll
  for (int t = 0; t < 4; ++t) {
    float oy = y0 + (float)(t >> 1);
    float ox = x0 + (float)(t & 1);
    bool valid = (oy >= 0.f) && (oy <= 95.f) && (ox >= 0.f) && (ox <= 95.f);
    int yi = (int)fminf(fmaxf(oy, 0.f), 95.f);
    int xi = (int)fminf(fmaxf(ox, 0.f), 95.f);
    idx[t] = (yi + 1) * 128 + (xi + 1);
    wt[t] = valid ? wy[t >> 1] * wx[t & 1] : 0.f;
  }
  size_t e = (size_t)b * TABSTRIDE + (size_t)k * HW + px;
  tabi[e] = make_int4(idx[0], idx[1], idx[2], idx[3]);
  tabw[e] = make_float4(wt[0], wt[1], wt[2], wt[3]);
}

// ---------------- sampled from ftp: samp[px][kloc*C+c], row stride rowK ----
// grid (144, C/64, 2*nk); z: b = z&1, kloc = z>>1; k = kbase + kloc
__global__ void __launch_bounds__(256) k_sample_t(
    const unsigned short* __restrict__ ftp,
    const int4* __restrict__ tabi, const float4* __restrict__ tabw,
    unsigned short* __restrict__ samp, int C, int kbase, int rowK) {
  const int z = blockIdx.z;
  const int b = z & 1, kloc = z >> 1;
  const int k = kbase + kloc;
  const int t = threadIdx.x;
  const int px = blockIdx.x * 64 + (t >> 2);
  const int c = blockIdx.y * 64 + (t & 3) * 16;
  const unsigned short* fb = ftp + (size_t)b * FTPROWS * C + 128 * C;
  size_t e = (size_t)b * TABSTRIDE + (size_t)k * HW + px;
  int4 id = tabi[e];
  float4 wt = tabw[e];
  float acc[16];
#pragma unroll
  for (int j = 0; j < 16; ++j) acc[j] = 0.f;
  const int ids[4] = {id.x, id.y, id.z, id.w};
  const float wts[4] = {wt.x, wt.y, wt.z, wt.w};
#pragma unroll
  for (int s = 0; s < 4; ++s) {
    const unsigned short* p = fb + (size_t)ids[s] * C + c;
    u16x8 v0 = *(const u16x8*)p;
    u16x8 v1 = *(const u16x8*)(p + 8);
    float wgt = wts[s];
#pragma unroll
    for (int j = 0; j < 8; ++j) acc[j] += wgt * bf2f(v0[j]);
#pragma unroll
    for (int j = 0; j < 8; ++j) acc[8 + j] += wgt * bf2f(v1[j]);
  }
  u16x8 o0, o1;
#pragma unroll
  for (int j = 0; j < 8; ++j) o0[j] = f2bf(acc[j]);
#pragma unroll
  for (int j = 0; j < 8; ++j) o1[j] = f2bf(acc[8 + j]);
  unsigned short* dst = samp + ((size_t)b * HW + px) * rowK + kloc * C + c;
  *(u16x8*)dst = o0;
  *(u16x8*)(dst + 8) = o1;
}

// ---------------- weight prep: Ap[m][k*C+c] = dw[m][c][k] (bf16) ----------
__global__ void k_prepA(const float* __restrict__ dw, unsigned short* __restrict__ Ap,
                        int C) {
  int o = blockIdx.x * 256 + threadIdx.x;
  int K = 9 * C;
  int m = o / K, r = o - m * K;
  int k = r / C, c = r - k * C;
  Ap[o] = f2bf(dw[((size_t)m * C + c) * 9 + k]);
}

// ---- staging: 2 A-GLDS + 2 B-GLDS per wave; rows 64B, unit swz u^((row>>1)&3)
__device__ __forceinline__ void stage_ab32(const unsigned short* __restrict__ Ag,
                                           const unsigned short* __restrict__ Bg,
                                           int lda, int rowK, int kt,
                                           unsigned short* as_, unsigned short* bs_,
                                           int wv, int lane) {
  const int lr = lane >> 2;          // row within 16-row GLDS block
  const int lu = lane & 3;           // 16B unit within 64B row
#pragma unroll
  for (int q = 0; q < 2; ++q) {
    int row = wv * 32 + q * 16 + lr;
    int su = lu ^ ((row >> 1) & 3);
    GLDS(Ag + (size_t)row * lda + kt + su * 8, (char*)as_ + (wv * 2 + q) * 1024);
  }
#pragma unroll
  for (int q = 0; q < 2; ++q) {
    int row = wv * 32 + q * 16 + lr;
    int su = lu ^ ((row >> 1) & 3);
    GLDS(Bg + (size_t)row * rowK + kt + su * 8, (char*)bs_ + (wv * 2 + q) * 1024);
  }
}

// ---------------- bf16 MFMA GEMM: 128x128, BK=32, 3-stage pipeline ---------
// grid (72, M/128, 2), 256 thr (2x2 waves of 64x64). 4 GLDS/wave/tile.
__global__ void __launch_bounds__(256) k_dcgemm(
    const unsigned short* __restrict__ Ap, const unsigned short* __restrict__ Bt,
    float* __restrict__ Y, int lda, int rowK, int aOff, int accum) {
  __shared__ unsigned short As[3][128 * 32];  // 3 x 8 KB
  __shared__ unsigned short Bs[3][128 * 32];  // 3 x 8 KB
  const int tid = threadIdx.x;
  const int lane = tid & 63, wv = tid >> 6;
  const int b = blockIdx.z;
  const int m0 = blockIdx.y << 7, n0 = blockIdx.x << 7;
  const unsigned short* Ag = Ap + (size_t)m0 * lda + aOff;
  const unsigned short* Bg = Bt + ((size_t)b * HW + n0) * rowK;

  const int wm = (wv >> 1) * 64, wn = (wv & 1) * 64;
  const int fr = lane & 15, hi = lane >> 4;
  const int nt = rowK >> 5;

  f32x4 acc[4][4];
#pragma unroll
  for (int i = 0; i < 4; ++i)
#pragma unroll
    for (int j = 0; j < 4; ++j) acc[i][j] = (f32x4){0.f, 0.f, 0.f, 0.f};

  stage_ab32(Ag, Bg, lda, rowK, 0,  &As[0][0], &Bs[0][0], wv, lane);
  stage_ab32(Ag, Bg, lda, rowK, 32, &As[1][0], &Bs[1][0], wv, lane);

  for (int t = 0; t < nt; ++t) {
    const int cur = t % 3;
    if (t + 2 < nt) {
      stage_ab32(Ag, Bg, lda, rowK, (t + 2) << 5, &As[(t + 2) % 3][0],
                 &Bs[(t + 2) % 3][0], wv, lane);
      asm volatile("s_waitcnt vmcnt(8)" ::: "memory");  // tile t done; t+1,t+2 in flight
    } else if (t + 1 < nt) {
      asm volatile("s_waitcnt vmcnt(4)" ::: "memory");
    } else {
      asm volatile("s_waitcnt vmcnt(0)" ::: "memory");
    }
    __builtin_amdgcn_s_barrier();
    __builtin_amdgcn_sched_barrier(0);
    bf16x8 a[4], bb[4];
#pragma unroll
    for (int i = 0; i < 4; ++i) {
      int row = wm + i * 16 + fr;
      a[i] = *(const bf16x8*)&As[cur][row * 32 + ((hi ^ ((row >> 1) & 3)) * 8)];
    }
#pragma unroll
    for (int j = 0; j < 4; ++j) {
      int row = wn + j * 16 + fr;
      bb[j] = *(const bf16x8*)&Bs[cur][row * 32 + ((hi ^ ((row >> 1) & 3)) * 8)];
    }
    __builtin_amdgcn_s_setprio(1);
#pragma unroll
    for (int i = 0; i < 4; ++i)
#pragma unroll
      for (int j = 0; j < 4; ++j)
        acc[i][j] = __builtin_amdgcn_mfma_f32_16x16x32_bf16(a[i], bb[j], acc[i][j], 0, 0, 0);
    __builtin_amdgcn_s_setprio(0);
    __builtin_amdgcn_s_barrier();  // frag reads of buf[cur] done before overwrite
  }

  float* Yb = Y + (size_t)b * FSTRIDE;
  const int orow = m0 + wm + hi * 4;
  const int ocol = n0 + wn + fr;
#pragma unroll
  for (int i = 0; i < 4; ++i) {
#pragma unroll
    for (int j = 0; j < 4; ++j) {
      float* p = Yb + (size_t)(orow + i * 16) * HW + ocol + j * 16;
#pragma unroll
      for (int q = 0; q < 4; ++q) {
        float v = acc[i][j][q];
        if (accum) v += p[(size_t)q * HW];
        p[(size_t)q * HW] = v;
      }
    }
  }
}

// ---------------- GroupNorm stats: stage 1 ----------------
__global__ void __launch_bounds__(256) k_gnstats1(const float* __restrict__ y,
                                                  float2* __restrict__ part, int CperG) {
  const int b = blockIdx.z, g = blockIdx.x, ch = blockIdx.y;
  const int n = CperG * HW;
  const int cs = n >> 4;
  const int cs4 = cs >> 2;
  const float4* p = (const float4*)(y + (size_t)b * FSTRIDE + (size_t)g * n + (size_t)ch * cs);
  float s = 0.f, q = 0.f;
  for (int i = threadIdx.x; i < cs4; i += 256) {
    float4 v = p[i];
    s += v.x + v.y + v.z + v.w;
    q += v.x * v.x + v.y * v.y + v.z * v.z + v.w * v.w;
  }
  __shared__ float ss[256], qs[256];
  ss[threadIdx.x] = s; qs[threadIdx.x] = q;
  __syncthreads();
  for (int d = 128; d > 0; d >>= 1) {
    if (threadIdx.x < d) { ss[threadIdx.x] += ss[threadIdx.x + d]; qs[threadIdx.x] += qs[threadIdx.x + d]; }
    __syncthreads();
  }
  if (threadIdx.x == 0) part[((b << 5) + g) * 16 + ch] = make_float2(ss[0], qs[0]);
}

// ---------------- GroupNorm stats: stage 2 ----------------
__global__ void k_gnfin(const float2* __restrict__ part, float2* __restrict__ stat,
                        int CperG) {
  int t = threadIdx.x;
  float s = 0.f, q = 0.f;
#pragma unroll
  for (int j = 0; j < 16; ++j) { float2 v = part[t * 16 + j]; s += v.x; q += v.y; }
  float n = (float)(CperG * HW);
  float m = s / n;
  float var = q / n - m * m;
  stat[t] = make_float2(m, rsqrtf(var + 1e-5f));
}

// ---------------- GroupNorm apply + ReLU (float4) — layer 4 only ----------
__global__ void k_gnapply(const float* __restrict__ y, const float2* __restrict__ stat,
                          const float* __restrict__ gamma, const float* __restrict__ beta,
                          float* __restrict__ out, int CperG, size_t ostride) {
  int b = blockIdx.z;
  int i = (blockIdx.x * 256 + threadIdx.x) * 4;
  int c = i / HW;
  float2 st = stat[b * 32 + c / CperG];
  float ga = gamma[c], be = beta[c];
  float4 v = *(const float4*)(y + (size_t)b * FSTRIDE + i);
  v.x = fmaxf((v.x - st.x) * st.y * ga + be, 0.f);
  v.y = fmaxf((v.y - st.x) * st.y * ga + be, 0.f);
  v.z = fmaxf((v.z - st.x) * st.y * ga + be, 0.f);
  v.w = fmaxf((v.w - st.x) * st.y * ga + be, 0.f);
  *(float4*)(out + (size_t)b * ostride + i) = v;
}

// ---------------- cosine-sim: stage 1 ----------------
__global__ void k_cos1(const float* __restrict__ res, float4* __restrict__ part) {
  int px = blockIdx.x * 256 + threadIdx.x;
  int cc = blockIdx.y;
  float saa = 0.f, sbb = 0.f, sab = 0.f;
  for (int c = cc * 32; c < cc * 32 + 32; ++c) {
    float a = res[(size_t)c * HW + px];
    float bb = res[2 * (size_t)RSTRIDE + (size_t)c * HW + px];
    saa += a * a; sbb += bb * bb; sab += a * bb;
  }
  part[(size_t)cc * HW + px] = make_float4(saa, sbb, sab, 0.f);
}

// ---------------- cosine-sim: stage 2 ----------------
__global__ void k_cos2(const float4* __restrict__ part, float* __restrict__ wpix) {
  int px = blockIdx.x * 256 + threadIdx.x;
  float saa = 0.f, sbb = 0.f, sab = 0.f;
#pragma unroll
  for (int cc = 0; cc < 8; ++cc) {
    float4 v = part[(size_t)cc * HW + px];
    saa += v.x; sbb += v.y; sab += v.z;
  }
  float na = sqrtf(saa), nb = sqrtf(sbb);
  float ttw = saa / fmaxf(na * na, 1e-8f);
  float tkw = sab / fmaxf(na * nb, 1e-8f);
  float m = fmaxf(ttw, tkw);
  float e0 = expf(ttw - m), e1 = expf(tkw - m);
  wpix[px] = e0 / (e0 + e1);
}

// ---------------- final blend ----------------
__global__ void k_combine(const float* __restrict__ res, const float* __restrict__ wpix,
                          float* __restrict__ out) {
  int i = blockIdx.x * 256 + threadIdx.x;
  int px = i % HW;
  float w0 = wpix[px];
  out[i] = w0 * res[i] + (1.f - w0) * res[2 * (size_t)RSTRIDE + i];
}

extern "C" void kernel_launch(void* const* d_in, const int* in_sizes, int n_in,
                              void* d_out, int out_size, void* d_ws, size_t ws_size,
                              hipStream_t stream) {
  const float* datas = (const float*)d_in[0];
  const float* ow[4] = {(const float*)d_in[1], (const float*)d_in[6],
                        (const float*)d_in[11], (const float*)d_in[16]};
  const float* ob[4] = {(const float*)d_in[2], (const float*)d_in[7],
                        (const float*)d_in[12], (const float*)d_in[17]};
  const float* dw[4] = {(const float*)d_in[3], (const float*)d_in[8],
                        (const float*)d_in[13], (const float*)d_in[18]};
  const float* gg[4] = {(const float*)d_in[4], (const float*)d_in[9],
                        (const float*)d_in[14], (const float*)d_in[19]};
  const float* gb[4] = {(const float*)d_in[5], (const float*)d_in[10],
                        (const float*)d_in[15], (const float*)d_in[20]};

  // full-K needs 255.02 MB (ftp256 aliased into samp tail); else 3-chunk.
  const int fullk = (ws_size >= 255100000ull) ? 1 : 0;
  const size_t sampN = fullk ? (2 * (size_t)HW * 4608) : (2 * (size_t)HW * 1536);

  float* ws = (float*)d_ws;
  float* y     = ws;                                      // 2*FSTRIDE fp32
  float* offp3 = y + 2 * (size_t)FSTRIDE;                 // 2*3*PXP*32 fp32
  float4* tabw = (float4*)(offp3 + 2 * 3 * (size_t)PXP * 32);
  int4*   tabi = (int4*)(tabw + 2 * (size_t)TABSTRIDE);
  float* wpix = (float*)(tabi + 2 * (size_t)TABSTRIDE);   // HW
  float2* stat = (float2*)(wpix + HW);                    // 64
  float2* gnpart = stat + 64;                             // 1024
  float4* cospart = (float4*)(gnpart + 1024);             // 8*HW
  float* endp = (float*)(cospart + 8 * (size_t)HW);
  size_t ofs = ((size_t)(endp - ws) + 3) & ~(size_t)3;
  unsigned short* samp = (unsigned short*)(ws + ofs);
  unsigned short* Ap = samp + sampN;                      // 512*4608
  unsigned short* Wt = Ap + (size_t)512 * 4608;           // 9*32*512
  unsigned short* ftp512 = Wt + (size_t)9 * 32 * 512;     // 2*FTPROWS*512
  unsigned short* ftp256 = fullk ? (samp + 2 * (size_t)HW * 2304)
                                 : (ftp512 + 2 * (size_t)FTPROWS * 512);

  dim3 blk(256);
  k_zero<<<dim3(2 * FTPROWS * 512 / 8 / 256), blk, 0, stream>>>(ftp512, 2u * FTPROWS * 512 / 8);

  for (int l = 0; l < 4; ++l) {
    const int Cx = (l < 3) ? 512 : 256;
    const int M  = Cx;
    if (l == 0) {
      k_mkftp_cat<<<dim3(144, 8, 2), blk, 0, stream>>>(datas + RSTRIDE, datas,
                                                       datas + RSTRIDE, ftp512, 512, 256);
    } else {
      k_gnstats1<<<dim3(32, 16, 2), blk, 0, stream>>>(y, gnpart, 16);
      k_gnfin<<<dim3(1), dim3(64), 0, stream>>>(gnpart, stat, 16);
      k_mkftp_gn<<<dim3(144, 8, 2), blk, 0, stream>>>(y, stat, gg[l - 1], gb[l - 1], ftp512);
    }
    k_prepA<<<dim3(M * 9 * Cx / 256), blk, 0, stream>>>(dw[l], Ap, Cx);
    k_prepW<<<dim3(9 * 32 * 512 / 256), blk, 0, stream>>>(ow[l], Wt);
    k_offmm<<<dim3(96, 3, 2), blk, 0, stream>>>(ftp512, Wt, offp3);
    k_table<<<dim3(36, 9, 2), blk, 0, stream>>>(offp3, ob[l], tabi, tabw);
    const unsigned short* sftp;
    if (l < 3) {
      sftp = ftp512;
    } else {
      k_zero<<<dim3(2 * FTPROWS * 256 / 8 / 256), blk, 0, stream>>>(ftp256, 2u * FTPROWS * 256 / 8);
      k_mkftp_cat<<<dim3(144, 4, 2), blk, 0, stream>>>(datas + RSTRIDE, datas,
                                                       datas, ftp256, 256, 256);
      sftp = ftp256;
    }
    const int nch = fullk ? 1 : 3;
    const int nk = 9 / nch;
    const int rowK = nk * Cx;
    for (int ch = 0; ch < nch; ++ch) {
      k_sample_t<<<dim3(144, Cx / 64, 2 * nk), blk, 0, stream>>>(sftp, tabi, tabw, samp,
                                                                 Cx, ch * nk, rowK);
      k_dcgemm<<<dim3(72, M / 128, 2), blk, 0, stream>>>(Ap, samp, y, 9 * Cx, rowK,
                                                         ch * rowK, ch > 0);
    }
  }

  // layer-4 GN -> res, then cosine blend
  k_gnstats1<<<dim3(32, 16, 2), blk, 0, stream>>>(y, gnpart, 8);
  k_gnfin<<<dim3(1), dim3(64), 0, stream>>>(gnpart, stat, 8);
  float* res = y + RSTRIDE;  // b-stride 2*RSTRIDE (upper halves of y are free)
  k_gnapply<<<dim3(RSTRIDE / 1024, 1, 2), blk, 0, stream>>>(y, stat, gg[3], gb[3], res,
                                                            8, 2 * (size_t)RSTRIDE);
  k_cos1<<<dim3(36, 8), blk, 0, stream>>>(res, cospart);
  k_cos2<<<dim3(36), blk, 0, stream>>>(cospart, wpix);
  k_combine<<<dim3(RSTRIDE / 256), blk, 0, stream>>>(res, wpix, (float*)d_out);
}